// Round 2
// baseline (19286.052 us; speedup 1.0000x reference)
//
#include <hip/hip_runtime.h>
#include <cstdint>
#include <cstddef>

#define B_   4
#define V_   50000
#define K_   128
#define C_   128
#define NNZ_ 800000
#define HID_ 256

#define PLANE_FULL  (B_ * V_ * C_)       // 25,600,000 floats per d-plane (full)
#define PLANE_ONE   (V_ * C_)            // 6,400,000 floats per d-plane (1 batch)

// shared small buffers (both modes)
#define WS_XSPEC 0
#define WS_SPECS 65536
#define WS_BIG   131072                  // start of big region (x_diffuse)

// ============================================================================
// k_spec: x_spec[b,k,c] = sum_v evecs[b,v,k] * mass[b,v] * x_in[b,v,c]
// grid (196, nb), block 256. Each block reduces a 256-row V-slab into a full
// 128x128 tile held in registers (64/thread), then atomicAdd into x_spec.
// ============================================================================
__global__ __launch_bounds__(256) void k_spec(
    const float* __restrict__ evecs, const float* __restrict__ mass,
    const float* __restrict__ x_in, float* __restrict__ x_spec, int bbase)
{
    const int b   = bbase + blockIdx.y;
    const int vb  = blockIdx.x * 256;
    const int tid = threadIdx.x;
    const int tk  = tid & 15;   // owns k = 4*tk..+3 and 4*tk+64..+3
    const int tc  = tid >> 4;   // owns c = 4*tc..+3 and 4*tc+64..+3

    __shared__ float ev_s[32][128];
    __shared__ float xm_s[32][128];

    float acc[8][8];
#pragma unroll
    for (int i = 0; i < 8; ++i)
#pragma unroll
        for (int j = 0; j < 8; ++j) acc[i][j] = 0.f;

    for (int v0 = vb; v0 < vb + 256; v0 += 32) {
        __syncthreads();
#pragma unroll
        for (int it = 0; it < 4; ++it) {
            int f   = tid + it * 256;      // float4 slot 0..1023
            int row = f >> 5;
            int col = (f & 31) * 4;
            int v   = v0 + row;
            float4 e = make_float4(0.f, 0.f, 0.f, 0.f);
            float4 x = make_float4(0.f, 0.f, 0.f, 0.f);
            if (v < V_) {
                e = *(const float4*)&evecs[((size_t)b * V_ + v) * K_ + col];
                x = *(const float4*)&x_in [((size_t)b * V_ + v) * C_ + col];
                float m = mass[b * V_ + v];
                x.x *= m; x.y *= m; x.z *= m; x.w *= m;
            }
            *(float4*)&ev_s[row][col] = e;
            *(float4*)&xm_s[row][col] = x;
        }
        __syncthreads();
#pragma unroll 8
        for (int vv = 0; vv < 32; ++vv) {
            float4 e0 = *(const float4*)&ev_s[vv][tk * 4];
            float4 e1 = *(const float4*)&ev_s[vv][tk * 4 + 64];
            float4 x0 = *(const float4*)&xm_s[vv][tc * 4];
            float4 x1 = *(const float4*)&xm_s[vv][tc * 4 + 64];
            float ee[8] = {e0.x, e0.y, e0.z, e0.w, e1.x, e1.y, e1.z, e1.w};
            float xx[8] = {x0.x, x0.y, x0.z, x0.w, x1.x, x1.y, x1.z, x1.w};
#pragma unroll
            for (int i = 0; i < 8; ++i)
#pragma unroll
                for (int j = 0; j < 8; ++j)
                    acc[i][j] += ee[i] * xx[j];
        }
    }
#pragma unroll
    for (int i = 0; i < 8; ++i) {
        int k = tk * 4 + (i & 3) + (i >> 2) * 64;
#pragma unroll
        for (int j = 0; j < 8; ++j) {
            int c = tc * 4 + (j & 3) + (j >> 2) * 64;
            atomicAdd(&x_spec[((size_t)b * K_ + k) * C_ + c], acc[i][j]);
        }
    }
}

// ============================================================================
// k_scale: spec_s = exp(-evals[b,k] * max(dt[c],1e-8)) * x_spec
// ============================================================================
__global__ __launch_bounds__(256) void k_scale(
    const float* __restrict__ evals, const float* __restrict__ dt,
    const float* __restrict__ x_spec, float* __restrict__ spec_s, int base_i)
{
    int i  = base_i + blockIdx.x * 256 + threadIdx.x;
    int c  = i & (C_ - 1);
    int bk = i >> 7;                           // b*K + k
    float t = fmaxf(dt[c], 1e-8f);
    spec_s[i] = __expf(-evals[bk] * t) * x_spec[i];
}

// ============================================================================
// k_frombasis: x_diffuse[bw,v,c] = sum_k evecs[b,v,k] * spec_s[b,k,c]
// grid (782, nb). Tile 64(m) x 128(n), k-chunks of 16.
// ============================================================================
__global__ __launch_bounds__(256) void k_frombasis(
    const float* __restrict__ evecs, const float* __restrict__ spec_s,
    float* __restrict__ x_diffuse, int bbase, int ws_b0)
{
    const int b   = bbase + blockIdx.y;
    const int bw  = b - ws_b0;
    const int v0  = blockIdx.x * 64;
    const int tid = threadIdx.x;
    const int tm  = tid & 15;   // m0 = 4*tm
    const int tn  = tid >> 4;   // n quads at 4*tn and 4*tn+64

    __shared__ float As[16][64];
    __shared__ float Ws[16][128];

    float acc[4][8];
#pragma unroll
    for (int i = 0; i < 4; ++i)
#pragma unroll
        for (int j = 0; j < 8; ++j) acc[i][j] = 0.f;

    for (int k0 = 0; k0 < K_; k0 += 16) {
        __syncthreads();
        {   // stage evecs tile transposed: As[kk][m]
            int m  = tid >> 2;
            int k4 = (tid & 3) * 4;
            int v  = v0 + m;
            float4 e = (v < V_)
                ? *(const float4*)&evecs[((size_t)b * V_ + v) * K_ + k0 + k4]
                : make_float4(0.f, 0.f, 0.f, 0.f);
            As[k4 + 0][m] = e.x; As[k4 + 1][m] = e.y;
            As[k4 + 2][m] = e.z; As[k4 + 3][m] = e.w;
        }
#pragma unroll
        for (int it = 0; it < 2; ++it) {   // stage spec rows direct: Ws[kk][n]
            int f   = tid + it * 256;      // 0..511 float4
            int kk  = f >> 5;
            int col = (f & 31) * 4;
            *(float4*)&Ws[kk][col] =
                *(const float4*)&spec_s[((size_t)b * K_ + k0 + kk) * C_ + col];
        }
        __syncthreads();
#pragma unroll
        for (int kk = 0; kk < 16; ++kk) {
            float4 a  = *(const float4*)&As[kk][tm * 4];
            float4 w0 = *(const float4*)&Ws[kk][tn * 4];
            float4 w1 = *(const float4*)&Ws[kk][tn * 4 + 64];
            float aa[4] = {a.x, a.y, a.z, a.w};
            float ww[8] = {w0.x, w0.y, w0.z, w0.w, w1.x, w1.y, w1.z, w1.w};
#pragma unroll
            for (int i = 0; i < 4; ++i)
#pragma unroll
                for (int j = 0; j < 8; ++j)
                    acc[i][j] += aa[i] * ww[j];
        }
    }
#pragma unroll
    for (int i = 0; i < 4; ++i) {
        int v = v0 + tm * 4 + i;
        if (v < V_) {
            float4 o0 = make_float4(acc[i][0], acc[i][1], acc[i][2], acc[i][3]);
            float4 o1 = make_float4(acc[i][4], acc[i][5], acc[i][6], acc[i][7]);
            *(float4*)&x_diffuse[((size_t)bw * V_ + v) * C_ + tn * 4]      = o0;
            *(float4*)&x_diffuse[((size_t)bw * V_ + v) * C_ + tn * 4 + 64] = o1;
        }
    }
}

// ============================================================================
// k_spmm: gout[bw,row,:] += val * x_diffuse[bw,col,:]   (scatter, atomic)
// grid (100000/nb..., nb): 32 threads per nnz, 4 channels per thread.
// ============================================================================
__global__ __launch_bounds__(256) void k_spmm(
    const float* __restrict__ vals, const int* __restrict__ rows,
    const int* __restrict__ cols, const float* __restrict__ x_diffuse,
    float* __restrict__ gout, int bbase, int ws_b0)
{
    const int b  = bbase + blockIdx.y;
    const int bw = b - ws_b0;
    int gid  = blockIdx.x * 256 + threadIdx.x;
    int lane = gid & 31;
    int e    = gid >> 5;               // < NNZ exactly
    float val = vals[(size_t)b * NNZ_ + e];
    int   r   = rows[(size_t)b * NNZ_ + e];
    int   c   = cols[(size_t)b * NNZ_ + e];
    float4 x = *(const float4*)&x_diffuse[((size_t)bw * V_ + c) * C_ + lane * 4];
    float* o = &gout[((size_t)bw * V_ + r) * C_ + lane * 4];
    atomicAdd(o + 0, val * x.x);
    atomicAdd(o + 1, val * x.y);
    atomicAdd(o + 2, val * x.z);
    atomicAdd(o + 3, val * x.w);
}

// ============================================================================
// k_gradfeat: Av = vflat @ A^T (tile 64m x 96n, n = 3c+d), then
// gf[bw,v,c] = tanh(sum_d Av[c,d] * g_d[bw,v,c]).  grid (782, 4, nb).
// ============================================================================
__global__ __launch_bounds__(256) void k_gradfeat(
    const float* __restrict__ g,      // 3 planes, d-stride = dplane
    const float* __restrict__ Aw,     // (384,384)
    float* __restrict__ gf, int bbase, int ws_b0, size_t dplane)
{
    const int b   = bbase + blockIdx.z;
    const int bw  = b - ws_b0;
    const int v0  = blockIdx.x * 64;
    const int ct  = blockIdx.y;       // 0..3 -> c0 = 32*ct, n0b = 96*ct
    const int tid = threadIdx.x;
    const int tm  = tid & 15;         // m0 = 4*tm
    const int tn  = tid >> 4;         // owns 6 n's: n0b + 6*tn ..+5
    const int c0  = ct * 32;
    const int n0b = ct * 96;

    __shared__ float As[48][64];
    __shared__ float Ws[48][96];

    float acc[4][6];
#pragma unroll
    for (int i = 0; i < 4; ++i)
#pragma unroll
        for (int j = 0; j < 6; ++j) acc[i][j] = 0.f;

    for (int k0 = 0; k0 < 384; k0 += 48) {
        __syncthreads();
        {   // stage vflat chunk: As[3*(c-ck0)+d][m] = g_d[bw,v,c]
            int ck0 = k0 / 3;          // 16 c per chunk
            int m   = tid >> 2;
            int c4  = (tid & 3) * 4;
            int v   = v0 + m;
#pragma unroll
            for (int d = 0; d < 3; ++d) {
                float4 gv = (v < V_)
                    ? *(const float4*)&g[(size_t)d * dplane + ((size_t)bw * V_ + v) * C_ + ck0 + c4]
                    : make_float4(0.f, 0.f, 0.f, 0.f);
                As[(c4 + 0) * 3 + d][m] = gv.x;
                As[(c4 + 1) * 3 + d][m] = gv.y;
                As[(c4 + 2) * 3 + d][m] = gv.z;
                As[(c4 + 3) * 3 + d][m] = gv.w;
            }
        }
        for (int f = tid; f < 1152; f += 256) {   // stage Aw chunk transposed
            int row = f / 12;
            int k4  = (f % 12) * 4;
            float4 w = *(const float4*)&Aw[(size_t)(n0b + row) * 384 + k0 + k4];
            Ws[k4 + 0][row] = w.x; Ws[k4 + 1][row] = w.y;
            Ws[k4 + 2][row] = w.z; Ws[k4 + 3][row] = w.w;
        }
        __syncthreads();
#pragma unroll 8
        for (int kk = 0; kk < 48; ++kk) {
            float4 a  = *(const float4*)&As[kk][tm * 4];
            float2 w0 = *(const float2*)&Ws[kk][tn * 6];
            float2 w1 = *(const float2*)&Ws[kk][tn * 6 + 2];
            float2 w2 = *(const float2*)&Ws[kk][tn * 6 + 4];
            float aa[4] = {a.x, a.y, a.z, a.w};
            float ww[6] = {w0.x, w0.y, w1.x, w1.y, w2.x, w2.y};
#pragma unroll
            for (int i = 0; i < 4; ++i)
#pragma unroll
                for (int j = 0; j < 6; ++j)
                    acc[i][j] += aa[i] * ww[j];
        }
    }
    // epilogue: contract over d with x_grad and tanh
#pragma unroll
    for (int i = 0; i < 4; ++i) {
        int v = v0 + tm * 4 + i;
        if (v >= V_) continue;
#pragma unroll
        for (int cc = 0; cc < 2; ++cc) {
            int c = c0 + tn * 2 + cc;
            float s = 0.f;
#pragma unroll
            for (int d = 0; d < 3; ++d)
                s += acc[i][cc * 3 + d] *
                     g[(size_t)d * dplane + ((size_t)bw * V_ + v) * C_ + c];
            gf[((size_t)bw * V_ + v) * C_ + c] = tanhf(s);
        }
    }
}

// ============================================================================
// k_mlp: f=[x_in|x_diffuse|gf]; h=relu(f@W0^T+b0) in LDS; out=h@W1^T+b1+x_in.
// 32 rows per block; ws rows [0,nrows), global rows offset by grow0.
// ============================================================================
__global__ __launch_bounds__(256) void k_mlp(
    const float* __restrict__ x_in, const float* __restrict__ x_diffuse,
    const float* __restrict__ gf,
    const float* __restrict__ W0, const float* __restrict__ b0,
    const float* __restrict__ W1, const float* __restrict__ b1,
    float* __restrict__ out, int grow0, int nrows)
{
    const int r0  = blockIdx.x * 32;   // ws-row base
    const int tid = threadIdx.x;
    const int tm  = tid & 15;          // m0 = 2*tm
    const int tn  = tid >> 4;

    __shared__ float As[16][32];
    __shared__ float Ws[16][256];
    __shared__ float Hs[32][257];      // pad 257: conflict-free scalar reads

    float acc[2][16];
#pragma unroll
    for (int i = 0; i < 2; ++i)
#pragma unroll
        for (int j = 0; j < 16; ++j) acc[i][j] = 0.f;

    for (int k0 = 0; k0 < 384; k0 += 16) {
        __syncthreads();
        if (tid < 128) {   // stage f chunk transposed
            int m    = tid >> 2;
            int k4   = (tid & 3) * 4;
            int col  = k0 + k4;
            int wr   = r0 + m;
            float4 a = make_float4(0.f, 0.f, 0.f, 0.f);
            if (wr < nrows) {
                if (col < 128)
                    a = *(const float4*)&x_in[(size_t)(grow0 + wr) * C_ + col];
                else if (col < 256)
                    a = *(const float4*)&x_diffuse[(size_t)wr * C_ + (col - 128)];
                else
                    a = *(const float4*)&gf[(size_t)wr * C_ + (col - 256)];
            }
            As[k4 + 0][m] = a.x; As[k4 + 1][m] = a.y;
            As[k4 + 2][m] = a.z; As[k4 + 3][m] = a.w;
        }
#pragma unroll
        for (int it = 0; it < 4; ++it) {   // stage W0 chunk transposed
            int f   = tid + it * 256;      // 0..1023 float4
            int row = f >> 2;
            int k4  = (f & 3) * 4;
            float4 w = *(const float4*)&W0[(size_t)row * 384 + k0 + k4];
            Ws[k4 + 0][row] = w.x; Ws[k4 + 1][row] = w.y;
            Ws[k4 + 2][row] = w.z; Ws[k4 + 3][row] = w.w;
        }
        __syncthreads();
#pragma unroll
        for (int kk = 0; kk < 16; ++kk) {
            float2 a  = *(const float2*)&As[kk][tm * 2];
            float4 w0 = *(const float4*)&Ws[kk][tn * 4];
            float4 w1 = *(const float4*)&Ws[kk][tn * 4 + 64];
            float4 w2 = *(const float4*)&Ws[kk][tn * 4 + 128];
            float4 w3 = *(const float4*)&Ws[kk][tn * 4 + 192];
            float ww[16] = {w0.x, w0.y, w0.z, w0.w, w1.x, w1.y, w1.z, w1.w,
                            w2.x, w2.y, w2.z, w2.w, w3.x, w3.y, w3.z, w3.w};
#pragma unroll
            for (int j = 0; j < 16; ++j) {
                acc[0][j] += a.x * ww[j];
                acc[1][j] += a.y * ww[j];
            }
        }
    }
    __syncthreads();
    // h = relu(acc + b0) -> Hs   (n = 4*tn + (j&3) + 64*(j>>2))
#pragma unroll
    for (int i = 0; i < 2; ++i)
#pragma unroll
        for (int j = 0; j < 16; ++j) {
            int n = tn * 4 + (j & 3) + (j >> 2) * 64;
            float h = acc[i][j] + b0[n];
            Hs[tm * 2 + i][n] = fmaxf(h, 0.f);
        }

    float acc2[2][8];
#pragma unroll
    for (int i = 0; i < 2; ++i)
#pragma unroll
        for (int j = 0; j < 8; ++j) acc2[i][j] = 0.f;

    for (int k0 = 0; k0 < 256; k0 += 16) {
        __syncthreads();
#pragma unroll
        for (int it = 0; it < 2; ++it) {   // stage W1 chunk transposed
            int f   = tid + it * 256;      // 0..511 float4
            int row = f >> 2;
            int k4  = (f & 3) * 4;
            float4 w = *(const float4*)&W1[(size_t)row * HID_ + k0 + k4];
            Ws[k4 + 0][row] = w.x; Ws[k4 + 1][row] = w.y;
            Ws[k4 + 2][row] = w.z; Ws[k4 + 3][row] = w.w;
        }
        __syncthreads();
#pragma unroll
        for (int kk = 0; kk < 16; ++kk) {
            float a0 = Hs[tm * 2 + 0][k0 + kk];
            float a1 = Hs[tm * 2 + 1][k0 + kk];
            float4 w0 = *(const float4*)&Ws[kk][tn * 4];
            float4 w1 = *(const float4*)&Ws[kk][tn * 4 + 64];
            float ww[8] = {w0.x, w0.y, w0.z, w0.w, w1.x, w1.y, w1.z, w1.w};
#pragma unroll
            for (int j = 0; j < 8; ++j) {
                acc2[0][j] += a0 * ww[j];
                acc2[1][j] += a1 * ww[j];
            }
        }
    }
    // epilogue: + b1 + x_in residual
#pragma unroll
    for (int i = 0; i < 2; ++i) {
        int wr = r0 + tm * 2 + i;
        if (wr >= nrows) continue;
        size_t grow = (size_t)(grow0 + wr);
#pragma unroll
        for (int h = 0; h < 2; ++h) {
            int n = tn * 4 + h * 64;
            float4 xi = *(const float4*)&x_in[grow * C_ + n];
            float4 o;
            o.x = acc2[i][h * 4 + 0] + b1[n + 0] + xi.x;
            o.y = acc2[i][h * 4 + 1] + b1[n + 1] + xi.y;
            o.z = acc2[i][h * 4 + 2] + b1[n + 2] + xi.z;
            o.w = acc2[i][h * 4 + 3] + b1[n + 3] + xi.w;
            *(float4*)&out[grow * C_ + n] = o;
        }
    }
}

// ============================================================================
extern "C" void kernel_launch(void* const* d_in, const int* in_sizes, int n_in,
                              void* d_out, int out_size, void* d_ws, size_t ws_size,
                              hipStream_t stream)
{
    const float* x_in  = (const float*)d_in[0];
    const float* evals = (const float*)d_in[1];
    const float* evecs = (const float*)d_in[2];
    const float* mass  = (const float*)d_in[3];
    const float* gv[3] = {(const float*)d_in[4], (const float*)d_in[7], (const float*)d_in[10]};
    const int*   gr[3] = {(const int*)d_in[5],   (const int*)d_in[8],   (const int*)d_in[11]};
    const int*   gc[3] = {(const int*)d_in[6],   (const int*)d_in[9],   (const int*)d_in[12]};
    const float* dt  = (const float*)d_in[13];
    const float* Aw  = (const float*)d_in[14];
    const float* W0  = (const float*)d_in[15];
    const float* b0  = (const float*)d_in[16];
    const float* W1  = (const float*)d_in[17];
    const float* b1  = (const float*)d_in[18];
    float* out = (float*)d_out;
    float* ws  = (float*)d_ws;

    float* x_spec = ws + WS_XSPEC;
    float* spec_s = ws + WS_SPECS;

    const size_t full_bytes  = ((size_t)WS_BIG + 5u * (size_t)PLANE_FULL) * 4u;
    const bool   full_mode   = ws_size >= full_bytes;

    hipMemsetAsync(x_spec, 0, 65536 * sizeof(float), stream);

    if (full_mode) {
        float* x_diff = ws + WS_BIG;
        float* g      = x_diff + PLANE_FULL;        // 3 consecutive planes
        float* gf     = g + 3 * (size_t)PLANE_FULL;

        hipMemsetAsync(g, 0, (size_t)3 * PLANE_FULL * sizeof(float), stream);

        k_spec<<<dim3(196, B_), 256, 0, stream>>>(evecs, mass, x_in, x_spec, 0);
        k_scale<<<dim3(256), 256, 0, stream>>>(evals, dt, x_spec, spec_s, 0);
        k_frombasis<<<dim3(782, B_), 256, 0, stream>>>(evecs, spec_s, x_diff, 0, 0);
        for (int d = 0; d < 3; ++d)
            k_spmm<<<dim3(100000, B_), 256, 0, stream>>>(
                gv[d], gr[d], gc[d], x_diff, g + (size_t)d * PLANE_FULL, 0, 0);
        k_gradfeat<<<dim3(782, 4, B_), 256, 0, stream>>>(g, Aw, gf, 0, 0, (size_t)PLANE_FULL);
        k_mlp<<<dim3(6250), 256, 0, stream>>>(x_in, x_diff, gf, W0, b0, W1, b1, out, 0, B_ * V_);
    } else {
        // per-batch path: ~128.5 MB of workspace
        float* x_diff = ws + WS_BIG;
        float* g      = x_diff + PLANE_ONE;         // 3 consecutive planes
        float* gf     = g + 3 * (size_t)PLANE_ONE;

        for (int b = 0; b < B_; ++b) {
            hipMemsetAsync(g, 0, (size_t)3 * PLANE_ONE * sizeof(float), stream);
            k_spec<<<dim3(196, 1), 256, 0, stream>>>(evecs, mass, x_in, x_spec, b);
            k_scale<<<dim3(64), 256, 0, stream>>>(evals, dt, x_spec, spec_s, b * K_ * C_);
            k_frombasis<<<dim3(782, 1), 256, 0, stream>>>(evecs, spec_s, x_diff, b, b);
            for (int d = 0; d < 3; ++d)
                k_spmm<<<dim3(100000, 1), 256, 0, stream>>>(
                    gv[d], gr[d], gc[d], x_diff, g + (size_t)d * PLANE_ONE, b, b);
            k_gradfeat<<<dim3(782, 4, 1), 256, 0, stream>>>(g, Aw, gf, b, b, (size_t)PLANE_ONE);
            k_mlp<<<dim3(1563), 256, 0, stream>>>(x_in, x_diff, gf, W0, b0, W1, b1, out, b * V_, V_);
        }
    }
}

// Round 3
// 5035.430 us; speedup vs baseline: 3.8301x; 3.8301x over previous
//
#include <hip/hip_runtime.h>
#include <cstdint>
#include <cstddef>

#define B_   4
#define V_   50000
#define K_   128
#define C_   128
#define NNZ_ 800000
#define HID_ 256

#define PLANE_ONE   (V_ * C_)            // 6,400,000 floats per d-plane (1 batch)

#define WS_XSPEC 0
#define WS_SPECS 65536
#define WS_BIG   131072                  // start of big region (x_diffuse)

#define CHUNK_  1024
#define NCHUNK_ 49                       // ceil(50000/1024)

// ============================================================================
// k_spec: x_spec[b,k,c] = sum_v evecs[b,v,k] * mass[b,v] * x_in[b,v,c]
// ============================================================================
__global__ __launch_bounds__(256) void k_spec(
    const float* __restrict__ evecs, const float* __restrict__ mass,
    const float* __restrict__ x_in, float* __restrict__ x_spec, int bbase)
{
    const int b   = bbase + blockIdx.y;
    const int vb  = blockIdx.x * 256;
    const int tid = threadIdx.x;
    const int tk  = tid & 15;
    const int tc  = tid >> 4;

    __shared__ float ev_s[32][128];
    __shared__ float xm_s[32][128];

    float acc[8][8];
#pragma unroll
    for (int i = 0; i < 8; ++i)
#pragma unroll
        for (int j = 0; j < 8; ++j) acc[i][j] = 0.f;

    for (int v0 = vb; v0 < vb + 256; v0 += 32) {
        __syncthreads();
#pragma unroll
        for (int it = 0; it < 4; ++it) {
            int f   = tid + it * 256;
            int row = f >> 5;
            int col = (f & 31) * 4;
            int v   = v0 + row;
            float4 e = make_float4(0.f, 0.f, 0.f, 0.f);
            float4 x = make_float4(0.f, 0.f, 0.f, 0.f);
            if (v < V_) {
                e = *(const float4*)&evecs[((size_t)b * V_ + v) * K_ + col];
                x = *(const float4*)&x_in [((size_t)b * V_ + v) * C_ + col];
                float m = mass[b * V_ + v];
                x.x *= m; x.y *= m; x.z *= m; x.w *= m;
            }
            *(float4*)&ev_s[row][col] = e;
            *(float4*)&xm_s[row][col] = x;
        }
        __syncthreads();
#pragma unroll 8
        for (int vv = 0; vv < 32; ++vv) {
            float4 e0 = *(const float4*)&ev_s[vv][tk * 4];
            float4 e1 = *(const float4*)&ev_s[vv][tk * 4 + 64];
            float4 x0 = *(const float4*)&xm_s[vv][tc * 4];
            float4 x1 = *(const float4*)&xm_s[vv][tc * 4 + 64];
            float ee[8] = {e0.x, e0.y, e0.z, e0.w, e1.x, e1.y, e1.z, e1.w};
            float xx[8] = {x0.x, x0.y, x0.z, x0.w, x1.x, x1.y, x1.z, x1.w};
#pragma unroll
            for (int i = 0; i < 8; ++i)
#pragma unroll
                for (int j = 0; j < 8; ++j)
                    acc[i][j] += ee[i] * xx[j];
        }
    }
#pragma unroll
    for (int i = 0; i < 8; ++i) {
        int k = tk * 4 + (i & 3) + (i >> 2) * 64;
#pragma unroll
        for (int j = 0; j < 8; ++j) {
            int c = tc * 4 + (j & 3) + (j >> 2) * 64;
            atomicAdd(&x_spec[((size_t)b * K_ + k) * C_ + c], acc[i][j]);
        }
    }
}

// ============================================================================
__global__ __launch_bounds__(256) void k_scale(
    const float* __restrict__ evals, const float* __restrict__ dt,
    const float* __restrict__ x_spec, float* __restrict__ spec_s, int base_i)
{
    int i  = base_i + blockIdx.x * 256 + threadIdx.x;
    int c  = i & (C_ - 1);
    int bk = i >> 7;
    float t = fmaxf(dt[c], 1e-8f);
    spec_s[i] = __expf(-evals[bk] * t) * x_spec[i];
}

// ============================================================================
// k_frombasis: x_diffuse[v,c] = sum_k evecs[b,v,k] * spec_s[b,k,c]
// ============================================================================
__global__ __launch_bounds__(256) void k_frombasis(
    const float* __restrict__ evecs, const float* __restrict__ spec_s,
    float* __restrict__ x_diffuse, int bbase)
{
    const int b   = bbase + blockIdx.y;
    const int v0  = blockIdx.x * 64;
    const int tid = threadIdx.x;
    const int tm  = tid & 15;
    const int tn  = tid >> 4;

    __shared__ float As[16][64];
    __shared__ float Ws[16][128];

    float acc[4][8];
#pragma unroll
    for (int i = 0; i < 4; ++i)
#pragma unroll
        for (int j = 0; j < 8; ++j) acc[i][j] = 0.f;

    for (int k0 = 0; k0 < K_; k0 += 16) {
        __syncthreads();
        {
            int m  = tid >> 2;
            int k4 = (tid & 3) * 4;
            int v  = v0 + m;
            float4 e = (v < V_)
                ? *(const float4*)&evecs[((size_t)b * V_ + v) * K_ + k0 + k4]
                : make_float4(0.f, 0.f, 0.f, 0.f);
            As[k4 + 0][m] = e.x; As[k4 + 1][m] = e.y;
            As[k4 + 2][m] = e.z; As[k4 + 3][m] = e.w;
        }
#pragma unroll
        for (int it = 0; it < 2; ++it) {
            int f   = tid + it * 256;
            int kk  = f >> 5;
            int col = (f & 31) * 4;
            *(float4*)&Ws[kk][col] =
                *(const float4*)&spec_s[((size_t)b * K_ + k0 + kk) * C_ + col];
        }
        __syncthreads();
#pragma unroll
        for (int kk = 0; kk < 16; ++kk) {
            float4 a  = *(const float4*)&As[kk][tm * 4];
            float4 w0 = *(const float4*)&Ws[kk][tn * 4];
            float4 w1 = *(const float4*)&Ws[kk][tn * 4 + 64];
            float aa[4] = {a.x, a.y, a.z, a.w};
            float ww[8] = {w0.x, w0.y, w0.z, w0.w, w1.x, w1.y, w1.z, w1.w};
#pragma unroll
            for (int i = 0; i < 4; ++i)
#pragma unroll
                for (int j = 0; j < 8; ++j)
                    acc[i][j] += aa[i] * ww[j];
        }
    }
#pragma unroll
    for (int i = 0; i < 4; ++i) {
        int v = v0 + tm * 4 + i;
        if (v < V_) {
            float4 o0 = make_float4(acc[i][0], acc[i][1], acc[i][2], acc[i][3]);
            float4 o1 = make_float4(acc[i][4], acc[i][5], acc[i][6], acc[i][7]);
            *(float4*)&x_diffuse[((size_t)v) * C_ + tn * 4]      = o0;
            *(float4*)&x_diffuse[((size_t)v) * C_ + tn * 4 + 64] = o1;
        }
    }
}

// ============================================================================
// CSR build: count -> chunksum -> chunkscan -> ptrwrite -> fill
// ============================================================================
__global__ __launch_bounds__(256) void k_count(
    const int* __restrict__ r0, const int* __restrict__ r1,
    const int* __restrict__ r2, int* __restrict__ cnt, int b)
{
    const int d = blockIdx.y;
    const int e = blockIdx.x * 256 + threadIdx.x;          // grid covers NNZ_ exactly
    const int* rr = (d == 0) ? r0 : (d == 1) ? r1 : r2;
    int r = rr[(size_t)b * NNZ_ + e];
    atomicAdd(&cnt[d * V_ + r], 1);
}

__global__ __launch_bounds__(256) void k_chunksum(
    const int* __restrict__ cnt, int* __restrict__ csum)
{
    const int d  = blockIdx.y;
    const int ch = blockIdx.x;
    const int tid = threadIdx.x;
    int s = 0;
#pragma unroll
    for (int j = 0; j < 4; ++j) {
        int i = ch * CHUNK_ + tid * 4 + j;
        if (i < V_) s += cnt[d * V_ + i];
    }
    __shared__ int sh[256];
    sh[tid] = s;
    __syncthreads();
    for (int off = 128; off > 0; off >>= 1) {
        if (tid < off) sh[tid] += sh[tid + off];
        __syncthreads();
    }
    if (tid == 0) csum[d * NCHUNK_ + ch] = sh[0];
}

__global__ __launch_bounds__(64) void k_chunkscan(
    int* __restrict__ csum, int* __restrict__ ptr)
{
    int d = threadIdx.x;
    if (d < 3) {
        int run = 0;
        for (int ch = 0; ch < NCHUNK_; ++ch) {
            int t = csum[d * NCHUNK_ + ch];
            csum[d * NCHUNK_ + ch] = run;
            run += t;
        }
        ptr[d * (V_ + 1) + V_] = NNZ_;     // sentinel
    }
}

__global__ __launch_bounds__(256) void k_ptrwrite(
    const int* __restrict__ cnt, const int* __restrict__ csum,
    int* __restrict__ ptr)
{
    const int d  = blockIdx.y;
    const int ch = blockIdx.x;
    const int tid = threadIdx.x;
    int v[4];
    int tsum = 0;
#pragma unroll
    for (int j = 0; j < 4; ++j) {
        int i = ch * CHUNK_ + tid * 4 + j;
        int x = (i < V_) ? cnt[d * V_ + i] : 0;
        v[j] = tsum;
        tsum += x;
    }
    __shared__ int sh[256];
    sh[tid] = tsum;
    __syncthreads();
    for (int off = 1; off < 256; off <<= 1) {
        int t = (tid >= off) ? sh[tid - off] : 0;
        __syncthreads();
        sh[tid] += t;
        __syncthreads();
    }
    int excl = sh[tid] - tsum;                 // exclusive over threads
    int base = csum[d * NCHUNK_ + ch] + excl;
#pragma unroll
    for (int j = 0; j < 4; ++j) {
        int i = ch * CHUNK_ + tid * 4 + j;
        if (i < V_) ptr[d * (V_ + 1) + i] = base + v[j];
    }
}

__global__ __launch_bounds__(256) void k_fill(
    const int* __restrict__ r0, const int* __restrict__ r1, const int* __restrict__ r2,
    const int* __restrict__ c0, const int* __restrict__ c1, const int* __restrict__ c2,
    const float* __restrict__ v0, const float* __restrict__ v1, const float* __restrict__ v2,
    const int* __restrict__ ptr, int* __restrict__ cnt,
    float* __restrict__ sv, int* __restrict__ sc, int b)
{
    const int d = blockIdx.y;
    const int e = blockIdx.x * 256 + threadIdx.x;
    const int*   rr = (d == 0) ? r0 : (d == 1) ? r1 : r2;
    const int*   cc = (d == 0) ? c0 : (d == 1) ? c1 : c2;
    const float* vv = (d == 0) ? v0 : (d == 1) ? v1 : v2;
    size_t src = (size_t)b * NNZ_ + e;
    int r = rr[src];
    int k = atomicSub(&cnt[d * V_ + r], 1) - 1;     // leaves cnt zeroed
    int pos = ptr[d * (V_ + 1) + r] + k;
    sv[(size_t)d * NNZ_ + pos] = vv[src];
    sc[(size_t)d * NNZ_ + pos] = cc[src];
}

// ============================================================================
// k_gather: g[d,r,:] = sum_{e in row r} sv[e] * x_diffuse[sc[e],:]
// one wave per row; float2 per lane. grid (12500, 3), block 256 (4 waves).
// ============================================================================
__global__ __launch_bounds__(256) void k_gather(
    const float* __restrict__ sv, const int* __restrict__ sc,
    const int* __restrict__ ptr, const float* __restrict__ x_diffuse,
    float* __restrict__ g)
{
    const int d    = blockIdx.y;
    const int w    = threadIdx.x >> 6;
    const int lane = threadIdx.x & 63;
    const int r    = blockIdx.x * 4 + w;            // 12500*4 = 50000 exact
    int beg = ptr[d * (V_ + 1) + r];
    int end = ptr[d * (V_ + 1) + r + 1];
    float2 acc = make_float2(0.f, 0.f);
    for (int i = beg; i < end; ++i) {
        float val = sv[(size_t)d * NNZ_ + i];
        int   c   = sc[(size_t)d * NNZ_ + i];
        float2 x = *(const float2*)&x_diffuse[(size_t)c * C_ + lane * 2];
        acc.x += val * x.x;
        acc.y += val * x.y;
    }
    *(float2*)&g[(size_t)d * PLANE_ONE + (size_t)r * C_ + lane * 2] = acc;
}

// ============================================================================
// k_gradfeat: Av = vflat @ A^T (tile 64m x 96n), then
// gf[v,c] = tanh(sum_d Av[c,d] * g_d[v,c]).  grid (782, 4).
// ============================================================================
__global__ __launch_bounds__(256) void k_gradfeat(
    const float* __restrict__ g, const float* __restrict__ Aw,
    float* __restrict__ gf)
{
    const int v0  = blockIdx.x * 64;
    const int ct  = blockIdx.y;
    const int tid = threadIdx.x;
    const int tm  = tid & 15;
    const int tn  = tid >> 4;
    const int c0  = ct * 32;
    const int n0b = ct * 96;

    __shared__ float As[48][64];
    __shared__ float Ws[48][96];

    float acc[4][6];
#pragma unroll
    for (int i = 0; i < 4; ++i)
#pragma unroll
        for (int j = 0; j < 6; ++j) acc[i][j] = 0.f;

    for (int k0 = 0; k0 < 384; k0 += 48) {
        __syncthreads();
        {
            int ck0 = k0 / 3;
            int m   = tid >> 2;
            int c4  = (tid & 3) * 4;
            int v   = v0 + m;
#pragma unroll
            for (int d = 0; d < 3; ++d) {
                float4 gv = (v < V_)
                    ? *(const float4*)&g[(size_t)d * PLANE_ONE + ((size_t)v) * C_ + ck0 + c4]
                    : make_float4(0.f, 0.f, 0.f, 0.f);
                As[(c4 + 0) * 3 + d][m] = gv.x;
                As[(c4 + 1) * 3 + d][m] = gv.y;
                As[(c4 + 2) * 3 + d][m] = gv.z;
                As[(c4 + 3) * 3 + d][m] = gv.w;
            }
        }
        for (int f = tid; f < 1152; f += 256) {
            int row = f / 12;
            int k4  = (f % 12) * 4;
            float4 w = *(const float4*)&Aw[(size_t)(n0b + row) * 384 + k0 + k4];
            Ws[k4 + 0][row] = w.x; Ws[k4 + 1][row] = w.y;
            Ws[k4 + 2][row] = w.z; Ws[k4 + 3][row] = w.w;
        }
        __syncthreads();
#pragma unroll 8
        for (int kk = 0; kk < 48; ++kk) {
            float4 a  = *(const float4*)&As[kk][tm * 4];
            float2 w0 = *(const float2*)&Ws[kk][tn * 6];
            float2 w1 = *(const float2*)&Ws[kk][tn * 6 + 2];
            float2 w2 = *(const float2*)&Ws[kk][tn * 6 + 4];
            float aa[4] = {a.x, a.y, a.z, a.w};
            float ww[6] = {w0.x, w0.y, w1.x, w1.y, w2.x, w2.y};
#pragma unroll
            for (int i = 0; i < 4; ++i)
#pragma unroll
                for (int j = 0; j < 6; ++j)
                    acc[i][j] += aa[i] * ww[j];
        }
    }
#pragma unroll
    for (int i = 0; i < 4; ++i) {
        int v = v0 + tm * 4 + i;
        if (v >= V_) continue;
#pragma unroll
        for (int cc = 0; cc < 2; ++cc) {
            int c = c0 + tn * 2 + cc;
            float s = 0.f;
#pragma unroll
            for (int d = 0; d < 3; ++d)
                s += acc[i][cc * 3 + d] *
                     g[(size_t)d * PLANE_ONE + ((size_t)v) * C_ + c];
            gf[((size_t)v) * C_ + c] = tanhf(s);
        }
    }
}

// ============================================================================
// k_mlp: f=[x_in|x_diffuse|gf]; h=relu(f@W0^T+b0) in LDS; out=h@W1^T+b1+x_in.
// ============================================================================
__global__ __launch_bounds__(256) void k_mlp(
    const float* __restrict__ x_in, const float* __restrict__ x_diffuse,
    const float* __restrict__ gf,
    const float* __restrict__ W0, const float* __restrict__ b0,
    const float* __restrict__ W1, const float* __restrict__ b1,
    float* __restrict__ out, int grow0, int nrows)
{
    const int r0  = blockIdx.x * 32;
    const int tid = threadIdx.x;
    const int tm  = tid & 15;
    const int tn  = tid >> 4;

    __shared__ float As[16][32];
    __shared__ float Ws[16][256];
    __shared__ float Hs[32][257];

    float acc[2][16];
#pragma unroll
    for (int i = 0; i < 2; ++i)
#pragma unroll
        for (int j = 0; j < 16; ++j) acc[i][j] = 0.f;

    for (int k0 = 0; k0 < 384; k0 += 16) {
        __syncthreads();
        if (tid < 128) {
            int m    = tid >> 2;
            int k4   = (tid & 3) * 4;
            int col  = k0 + k4;
            int wr   = r0 + m;
            float4 a = make_float4(0.f, 0.f, 0.f, 0.f);
            if (wr < nrows) {
                if (col < 128)
                    a = *(const float4*)&x_in[(size_t)(grow0 + wr) * C_ + col];
                else if (col < 256)
                    a = *(const float4*)&x_diffuse[(size_t)wr * C_ + (col - 128)];
                else
                    a = *(const float4*)&gf[(size_t)wr * C_ + (col - 256)];
            }
            As[k4 + 0][m] = a.x; As[k4 + 1][m] = a.y;
            As[k4 + 2][m] = a.z; As[k4 + 3][m] = a.w;
        }
#pragma unroll
        for (int it = 0; it < 4; ++it) {
            int f   = tid + it * 256;
            int row = f >> 2;
            int k4  = (f & 3) * 4;
            float4 w = *(const float4*)&W0[(size_t)row * 384 + k0 + k4];
            Ws[k4 + 0][row] = w.x; Ws[k4 + 1][row] = w.y;
            Ws[k4 + 2][row] = w.z; Ws[k4 + 3][row] = w.w;
        }
        __syncthreads();
#pragma unroll
        for (int kk = 0; kk < 16; ++kk) {
            float2 a  = *(const float2*)&As[kk][tm * 2];
            float4 w0 = *(const float4*)&Ws[kk][tn * 4];
            float4 w1 = *(const float4*)&Ws[kk][tn * 4 + 64];
            float4 w2 = *(const float4*)&Ws[kk][tn * 4 + 128];
            float4 w3 = *(const float4*)&Ws[kk][tn * 4 + 192];
            float ww[16] = {w0.x, w0.y, w0.z, w0.w, w1.x, w1.y, w1.z, w1.w,
                            w2.x, w2.y, w2.z, w2.w, w3.x, w3.y, w3.z, w3.w};
#pragma unroll
            for (int j = 0; j < 16; ++j) {
                acc[0][j] += a.x * ww[j];
                acc[1][j] += a.y * ww[j];
            }
        }
    }
    __syncthreads();
#pragma unroll
    for (int i = 0; i < 2; ++i)
#pragma unroll
        for (int j = 0; j < 16; ++j) {
            int n = tn * 4 + (j & 3) + (j >> 2) * 64;
            float h = acc[i][j] + b0[n];
            Hs[tm * 2 + i][n] = fmaxf(h, 0.f);
        }

    float acc2[2][8];
#pragma unroll
    for (int i = 0; i < 2; ++i)
#pragma unroll
        for (int j = 0; j < 8; ++j) acc2[i][j] = 0.f;

    for (int k0 = 0; k0 < 256; k0 += 16) {
        __syncthreads();
#pragma unroll
        for (int it = 0; it < 2; ++it) {
            int f   = tid + it * 256;
            int row = f >> 2;
            int k4  = (f & 3) * 4;
            float4 w = *(const float4*)&W1[(size_t)row * HID_ + k0 + k4];
            Ws[k4 + 0][row] = w.x; Ws[k4 + 1][row] = w.y;
            Ws[k4 + 2][row] = w.z; Ws[k4 + 3][row] = w.w;
        }
        __syncthreads();
#pragma unroll
        for (int kk = 0; kk < 16; ++kk) {
            float a0 = Hs[tm * 2 + 0][k0 + kk];
            float a1 = Hs[tm * 2 + 1][k0 + kk];
            float4 w0 = *(const float4*)&Ws[kk][tn * 4];
            float4 w1 = *(const float4*)&Ws[kk][tn * 4 + 64];
            float ww[8] = {w0.x, w0.y, w0.z, w0.w, w1.x, w1.y, w1.z, w1.w};
#pragma unroll
            for (int j = 0; j < 8; ++j) {
                acc2[0][j] += a0 * ww[j];
                acc2[1][j] += a1 * ww[j];
            }
        }
    }
#pragma unroll
    for (int i = 0; i < 2; ++i) {
        int wr = r0 + tm * 2 + i;
        if (wr >= nrows) continue;
        size_t grow = (size_t)(grow0 + wr);
#pragma unroll
        for (int h = 0; h < 2; ++h) {
            int n = tn * 4 + h * 64;
            float4 xi = *(const float4*)&x_in[grow * C_ + n];
            float4 o;
            o.x = acc2[i][h * 4 + 0] + b1[n + 0] + xi.x;
            o.y = acc2[i][h * 4 + 1] + b1[n + 1] + xi.y;
            o.z = acc2[i][h * 4 + 2] + b1[n + 2] + xi.z;
            o.w = acc2[i][h * 4 + 3] + b1[n + 3] + xi.w;
            *(float4*)&out[grow * C_ + n] = o;
        }
    }
}

// ============================================================================
extern "C" void kernel_launch(void* const* d_in, const int* in_sizes, int n_in,
                              void* d_out, int out_size, void* d_ws, size_t ws_size,
                              hipStream_t stream)
{
    const float* x_in  = (const float*)d_in[0];
    const float* evals = (const float*)d_in[1];
    const float* evecs = (const float*)d_in[2];
    const float* mass  = (const float*)d_in[3];
    const float* gv[3] = {(const float*)d_in[4], (const float*)d_in[7], (const float*)d_in[10]};
    const int*   gr[3] = {(const int*)d_in[5],   (const int*)d_in[8],   (const int*)d_in[11]};
    const int*   gc[3] = {(const int*)d_in[6],   (const int*)d_in[9],   (const int*)d_in[12]};
    const float* dt  = (const float*)d_in[13];
    const float* Aw  = (const float*)d_in[14];
    const float* W0  = (const float*)d_in[15];
    const float* b0  = (const float*)d_in[16];
    const float* W1  = (const float*)d_in[17];
    const float* b1  = (const float*)d_in[18];
    float* out = (float*)d_out;
    float* ws  = (float*)d_ws;

    float* x_spec = ws + WS_XSPEC;
    float* spec_s = ws + WS_SPECS;

    float* x_diff = ws + WS_BIG;                        // PLANE_ONE
    float* g      = x_diff + (size_t)PLANE_ONE;         // 3 * PLANE_ONE
    float* gfb    = g + 3 * (size_t)PLANE_ONE;          // PLANE_ONE region
    float* gf     = gfb;
    // CSR scratch aliases the gf region (dead before gf is written):
    float* sv   = gfb;                                  // 3*NNZ_ floats
    int*   sc   = (int*)(gfb + 3 * (size_t)NNZ_);       // 3*NNZ_ ints
    int*   ptr  = (int*)(gfb + 6 * (size_t)NNZ_);       // 3*(V_+1) ints
    int*   cnt  = ptr + 3 * (V_ + 1);                   // 3*V_ ints
    int*   csum = cnt + 3 * V_;                         // 3*NCHUNK_ ints

    hipMemsetAsync(x_spec, 0, 65536 * sizeof(float), stream);

    for (int b = 0; b < B_; ++b) {
        hipMemsetAsync(cnt, 0, 3 * V_ * sizeof(int), stream);
        k_spec<<<dim3(196, 1), 256, 0, stream>>>(evecs, mass, x_in, x_spec, b);
        k_scale<<<dim3(64), 256, 0, stream>>>(evals, dt, x_spec, spec_s, b * K_ * C_);
        k_frombasis<<<dim3(782, 1), 256, 0, stream>>>(evecs, spec_s, x_diff, b);
        // CSR build for the 3 gradient operators
        k_count<<<dim3(3125, 3), 256, 0, stream>>>(gr[0], gr[1], gr[2], cnt, b);
        k_chunksum<<<dim3(NCHUNK_, 3), 256, 0, stream>>>(cnt, csum);
        k_chunkscan<<<dim3(1), 64, 0, stream>>>(csum, ptr);
        k_ptrwrite<<<dim3(NCHUNK_, 3), 256, 0, stream>>>(cnt, csum, ptr);
        k_fill<<<dim3(3125, 3), 256, 0, stream>>>(
            gr[0], gr[1], gr[2], gc[0], gc[1], gc[2], gv[0], gv[1], gv[2],
            ptr, cnt, sv, sc, b);
        k_gather<<<dim3(12500, 3), 256, 0, stream>>>(sv, sc, ptr, x_diff, g);
        k_gradfeat<<<dim3(782, 4), 256, 0, stream>>>(g, Aw, gf);
        k_mlp<<<dim3(1563), 256, 0, stream>>>(x_in, x_diff, gf, W0, b0, W1, b1, out, b * V_, V_);
    }
}

// Round 4
// 3180.182 us; speedup vs baseline: 6.0644x; 1.5834x over previous
//
#include <hip/hip_runtime.h>
#include <cstdint>
#include <cstddef>

#define B_   4
#define V_   50000
#define VP_  50048                       // 782*64, padded row count
#define K_   128
#define C_   128
#define NNZ_ 800000
#define HID_ 256

#define CHUNK_  1024
#define NCHUNK_ 49

typedef __attribute__((ext_vector_type(8))) short short8;
typedef __attribute__((ext_vector_type(4))) float f32x4;

__device__ __forceinline__ unsigned short f2b(float f) {
    union { float f; unsigned u; } v; v.f = f;
    unsigned r = v.u + 0x7fffu + ((v.u >> 16) & 1u);
    return (unsigned short)(r >> 16);
}
__device__ __forceinline__ float b2f(unsigned short h) {
    union { unsigned u; float f; } v; v.u = ((unsigned)h) << 16; return v.f;
}
__device__ __forceinline__ unsigned pk(float lo, float hi) {
    return (unsigned)f2b(lo) | ((unsigned)f2b(hi) << 16);
}

// ============================================================================
// weight converts (once per launch)
// ============================================================================
__global__ __launch_bounds__(256) void k_cvt_w(
    const float* __restrict__ W0, const float* __restrict__ W1,
    unsigned short* __restrict__ W0b, unsigned short* __restrict__ W1b)
{
    int t = blockIdx.x * 256 + threadIdx.x;          // 16384 threads
    const float* src; unsigned short* dst; int i8;
    if (t < 12288) { i8 = t * 8;            src = W0 + i8; dst = W0b + i8; }
    else           { i8 = (t - 12288) * 8;  src = W1 + i8; dst = W1b + i8; }
    float4 x0 = *(const float4*)src;
    float4 x1 = *(const float4*)(src + 4);
    uint4 u;
    u.x = pk(x0.x, x0.y); u.y = pk(x0.z, x0.w);
    u.z = pk(x1.x, x1.y); u.w = pk(x1.z, x1.w);
    *(uint4*)dst = u;
}

// Awb[p1*384+p2] = bf16(Aw[q(p1)*384 + q(p2)]), q(p) = 3*(p&127) + (p>>7)
__global__ __launch_bounds__(256) void k_cvt_aw(
    const float* __restrict__ Aw, unsigned short* __restrict__ Awb)
{
    int p  = blockIdx.x * 256 + threadIdx.x;         // 147456 threads
    int p1 = p / 384, p2 = p - p1 * 384;
    int q1 = 3 * (p1 & 127) + (p1 >> 7);
    int q2 = 3 * (p2 & 127) + (p2 >> 7);
    Awb[p] = f2b(Aw[q1 * 384 + q2]);
}

// f[v][0:128] = bf16(x_in[b,v,:])
__global__ __launch_bounds__(256) void k_cvt_xin(
    const float* __restrict__ x_in, unsigned short* __restrict__ fb, int b)
{
    int idx = blockIdx.x * 256 + threadIdx.x;        // 800000 threads
    int v = idx >> 4;
    int c = (idx & 15) * 8;
    const float* src = &x_in[((size_t)b * V_ + v) * C_ + c];
    float4 x0 = *(const float4*)src;
    float4 x1 = *(const float4*)(src + 4);
    uint4 u;
    u.x = pk(x0.x, x0.y); u.y = pk(x0.z, x0.w);
    u.z = pk(x1.x, x1.y); u.w = pk(x1.z, x1.w);
    *(uint4*)&fb[(size_t)v * 384 + c] = u;
}

// ============================================================================
// k_spec: x_spec[b,k,c] = sum_v evecs[b,v,k] * mass[b,v] * x_in[b,v,c]  (fp32)
// ============================================================================
__global__ __launch_bounds__(256) void k_spec(
    const float* __restrict__ evecs, const float* __restrict__ mass,
    const float* __restrict__ x_in, float* __restrict__ x_spec, int bbase)
{
    const int b   = bbase + blockIdx.y;
    const int vb  = blockIdx.x * 256;
    const int tid = threadIdx.x;
    const int tk  = tid & 15;
    const int tc  = tid >> 4;

    __shared__ float ev_s[32][128];
    __shared__ float xm_s[32][128];

    float acc[8][8];
#pragma unroll
    for (int i = 0; i < 8; ++i)
#pragma unroll
        for (int j = 0; j < 8; ++j) acc[i][j] = 0.f;

    for (int v0 = vb; v0 < vb + 256; v0 += 32) {
        __syncthreads();
#pragma unroll
        for (int it = 0; it < 4; ++it) {
            int f   = tid + it * 256;
            int row = f >> 5;
            int col = (f & 31) * 4;
            int v   = v0 + row;
            float4 e = make_float4(0.f, 0.f, 0.f, 0.f);
            float4 x = make_float4(0.f, 0.f, 0.f, 0.f);
            if (v < V_) {
                e = *(const float4*)&evecs[((size_t)b * V_ + v) * K_ + col];
                x = *(const float4*)&x_in [((size_t)b * V_ + v) * C_ + col];
                float m = mass[b * V_ + v];
                x.x *= m; x.y *= m; x.z *= m; x.w *= m;
            }
            *(float4*)&ev_s[row][col] = e;
            *(float4*)&xm_s[row][col] = x;
        }
        __syncthreads();
#pragma unroll 8
        for (int vv = 0; vv < 32; ++vv) {
            float4 e0 = *(const float4*)&ev_s[vv][tk * 4];
            float4 e1 = *(const float4*)&ev_s[vv][tk * 4 + 64];
            float4 x0 = *(const float4*)&xm_s[vv][tc * 4];
            float4 x1 = *(const float4*)&xm_s[vv][tc * 4 + 64];
            float ee[8] = {e0.x, e0.y, e0.z, e0.w, e1.x, e1.y, e1.z, e1.w};
            float xx[8] = {x0.x, x0.y, x0.z, x0.w, x1.x, x1.y, x1.z, x1.w};
#pragma unroll
            for (int i = 0; i < 8; ++i)
#pragma unroll
                for (int j = 0; j < 8; ++j)
                    acc[i][j] += ee[i] * xx[j];
        }
    }
#pragma unroll
    for (int i = 0; i < 8; ++i) {
        int k = tk * 4 + (i & 3) + (i >> 2) * 64;
#pragma unroll
        for (int j = 0; j < 8; ++j) {
            int c = tc * 4 + (j & 3) + (j >> 2) * 64;
            atomicAdd(&x_spec[((size_t)b * K_ + k) * C_ + c], acc[i][j]);
        }
    }
}

// ============================================================================
__global__ __launch_bounds__(256) void k_scale(
    const float* __restrict__ evals, const float* __restrict__ dt,
    const float* __restrict__ x_spec, float* __restrict__ spec_s, int base_i)
{
    int i  = base_i + blockIdx.x * 256 + threadIdx.x;
    int c  = i & (C_ - 1);
    int bk = i >> 7;
    float t = fmaxf(dt[c], 1e-8f);
    spec_s[i] = __expf(-evals[bk] * t) * x_spec[i];
}

// ============================================================================
// k_frombasis: f[v][128+c] = bf16( sum_k evecs[b,v,k] * spec_s[b,k,c] )
// ============================================================================
__global__ __launch_bounds__(256) void k_frombasis(
    const float* __restrict__ evecs, const float* __restrict__ spec_s,
    unsigned short* __restrict__ fb, int bbase)
{
    const int b   = bbase + blockIdx.y;
    const int v0  = blockIdx.x * 64;
    const int tid = threadIdx.x;
    const int tm  = tid & 15;
    const int tn  = tid >> 4;

    __shared__ float As[16][64];
    __shared__ float Ws[16][128];

    float acc[4][8];
#pragma unroll
    for (int i = 0; i < 4; ++i)
#pragma unroll
        for (int j = 0; j < 8; ++j) acc[i][j] = 0.f;

    for (int k0 = 0; k0 < K_; k0 += 16) {
        __syncthreads();
        {
            int m  = tid >> 2;
            int k4 = (tid & 3) * 4;
            int v  = v0 + m;
            float4 e = (v < V_)
                ? *(const float4*)&evecs[((size_t)b * V_ + v) * K_ + k0 + k4]
                : make_float4(0.f, 0.f, 0.f, 0.f);
            As[k4 + 0][m] = e.x; As[k4 + 1][m] = e.y;
            As[k4 + 2][m] = e.z; As[k4 + 3][m] = e.w;
        }
#pragma unroll
        for (int it = 0; it < 2; ++it) {
            int f   = tid + it * 256;
            int kk  = f >> 5;
            int col = (f & 31) * 4;
            *(float4*)&Ws[kk][col] =
                *(const float4*)&spec_s[((size_t)b * K_ + k0 + kk) * C_ + col];
        }
        __syncthreads();
#pragma unroll
        for (int kk = 0; kk < 16; ++kk) {
            float4 a  = *(const float4*)&As[kk][tm * 4];
            float4 w0 = *(const float4*)&Ws[kk][tn * 4];
            float4 w1 = *(const float4*)&Ws[kk][tn * 4 + 64];
            float aa[4] = {a.x, a.y, a.z, a.w};
            float ww[8] = {w0.x, w0.y, w0.z, w0.w, w1.x, w1.y, w1.z, w1.w};
#pragma unroll
            for (int i = 0; i < 4; ++i)
#pragma unroll
                for (int j = 0; j < 8; ++j)
                    acc[i][j] += aa[i] * ww[j];
        }
    }
#pragma unroll
    for (int i = 0; i < 4; ++i) {
        int v = v0 + tm * 4 + i;
        if (v < V_) {
            uint2 u0, u1;
            u0.x = pk(acc[i][0], acc[i][1]); u0.y = pk(acc[i][2], acc[i][3]);
            u1.x = pk(acc[i][4], acc[i][5]); u1.y = pk(acc[i][6], acc[i][7]);
            *(uint2*)&fb[(size_t)v * 384 + 128 + tn * 4]      = u0;
            *(uint2*)&fb[(size_t)v * 384 + 128 + tn * 4 + 64] = u1;
        }
    }
}

// ============================================================================
// CSR build: count -> chunksum -> chunkscan -> ptrwrite -> fill
// ============================================================================
__global__ __launch_bounds__(256) void k_count(
    const int* __restrict__ r0, const int* __restrict__ r1,
    const int* __restrict__ r2, int* __restrict__ cnt, int b)
{
    const int d = blockIdx.y;
    const int e = blockIdx.x * 256 + threadIdx.x;
    const int* rr = (d == 0) ? r0 : (d == 1) ? r1 : r2;
    int r = rr[(size_t)b * NNZ_ + e];
    atomicAdd(&cnt[d * V_ + r], 1);
}

__global__ __launch_bounds__(256) void k_chunksum(
    const int* __restrict__ cnt, int* __restrict__ csum)
{
    const int d  = blockIdx.y;
    const int ch = blockIdx.x;
    const int tid = threadIdx.x;
    int s = 0;
#pragma unroll
    for (int j = 0; j < 4; ++j) {
        int i = ch * CHUNK_ + tid * 4 + j;
        if (i < V_) s += cnt[d * V_ + i];
    }
    __shared__ int sh[256];
    sh[tid] = s;
    __syncthreads();
    for (int off = 128; off > 0; off >>= 1) {
        if (tid < off) sh[tid] += sh[tid + off];
        __syncthreads();
    }
    if (tid == 0) csum[d * NCHUNK_ + ch] = sh[0];
}

__global__ __launch_bounds__(64) void k_chunkscan(
    int* __restrict__ csum, int* __restrict__ ptr)
{
    int d = threadIdx.x;
    if (d < 3) {
        int run = 0;
        for (int ch = 0; ch < NCHUNK_; ++ch) {
            int t = csum[d * NCHUNK_ + ch];
            csum[d * NCHUNK_ + ch] = run;
            run += t;
        }
        ptr[d * (V_ + 1) + V_] = NNZ_;
    }
}

__global__ __launch_bounds__(256) void k_ptrwrite(
    const int* __restrict__ cnt, const int* __restrict__ csum,
    int* __restrict__ ptr)
{
    const int d  = blockIdx.y;
    const int ch = blockIdx.x;
    const int tid = threadIdx.x;
    int v[4];
    int tsum = 0;
#pragma unroll
    for (int j = 0; j < 4; ++j) {
        int i = ch * CHUNK_ + tid * 4 + j;
        int x = (i < V_) ? cnt[d * V_ + i] : 0;
        v[j] = tsum;
        tsum += x;
    }
    __shared__ int sh[256];
    sh[tid] = tsum;
    __syncthreads();
    for (int off = 1; off < 256; off <<= 1) {
        int t = (tid >= off) ? sh[tid - off] : 0;
        __syncthreads();
        sh[tid] += t;
        __syncthreads();
    }
    int excl = sh[tid] - tsum;
    int base = csum[d * NCHUNK_ + ch] + excl;
#pragma unroll
    for (int j = 0; j < 4; ++j) {
        int i = ch * CHUNK_ + tid * 4 + j;
        if (i < V_) ptr[d * (V_ + 1) + i] = base + v[j];
    }
}

__global__ __launch_bounds__(256) void k_fill(
    const int* __restrict__ r0, const int* __restrict__ r1, const int* __restrict__ r2,
    const int* __restrict__ c0, const int* __restrict__ c1, const int* __restrict__ c2,
    const float* __restrict__ v0, const float* __restrict__ v1, const float* __restrict__ v2,
    const int* __restrict__ ptr, int* __restrict__ cnt,
    float* __restrict__ sv, int* __restrict__ sc, int b)
{
    const int d = blockIdx.y;
    const int e = blockIdx.x * 256 + threadIdx.x;
    const int*   rr = (d == 0) ? r0 : (d == 1) ? r1 : r2;
    const int*   cc = (d == 0) ? c0 : (d == 1) ? c1 : c2;
    const float* vv = (d == 0) ? v0 : (d == 1) ? v1 : v2;
    size_t src = (size_t)b * NNZ_ + e;
    int r = rr[src];
    int k = atomicSub(&cnt[d * V_ + r], 1) - 1;
    int pos = ptr[d * (V_ + 1) + r] + k;
    sv[(size_t)d * NNZ_ + pos] = vv[src];
    sc[(size_t)d * NNZ_ + pos] = cc[src];
}

// ============================================================================
// k_gather: vf[r][d*128+c] = bf16( sum_e sv[e] * x_diffuse_bf16[sc[e]][c] )
// x_diffuse read from f cols 128..255. One wave per row.
// ============================================================================
__global__ __launch_bounds__(256) void k_gather(
    const float* __restrict__ sv, const int* __restrict__ sc,
    const int* __restrict__ ptr, const unsigned short* __restrict__ fb,
    unsigned short* __restrict__ vf)
{
    const int d    = blockIdx.y;
    const int w    = threadIdx.x >> 6;
    const int lane = threadIdx.x & 63;
    const int r    = blockIdx.x * 4 + w;
    int beg = ptr[d * (V_ + 1) + r];
    int end = ptr[d * (V_ + 1) + r + 1];
    float ax = 0.f, ay = 0.f;
    for (int i = beg; i < end; ++i) {
        float val = sv[(size_t)d * NNZ_ + i];
        int   c   = sc[(size_t)d * NNZ_ + i];
        unsigned u = *(const unsigned*)&fb[(size_t)c * 384 + 128 + lane * 2];
        ax += val * b2f((unsigned short)(u & 0xffffu));
        ay += val * b2f((unsigned short)(u >> 16));
    }
    *(unsigned*)&vf[(size_t)r * 384 + d * 128 + lane * 2] = pk(ax, ay);
}

// ============================================================================
// k_gf_mfma: Av' = vf @ Awb^T (MFMA bf16), then
// f[v][256+c] = bf16(tanh(sum_d Av'[v][d*128+c] * vf[v][d*128+c]))
// block: 64 rows, 4 waves; wave w owns c in [32w, 32w+32)
// ============================================================================
__global__ __launch_bounds__(256) void k_gf_mfma(
    const unsigned short* __restrict__ vf,
    const unsigned short* __restrict__ Awb,
    unsigned short* __restrict__ fb)
{
    const int v0  = blockIdx.x * 64;
    const int tid = threadIdx.x;
    const int w   = tid >> 6;
    const int lr  = tid & 15;
    const int lk  = (tid & 63) >> 4;

    f32x4 z = {0.f, 0.f, 0.f, 0.f};
    f32x4 acc[4][3][2];
#pragma unroll
    for (int mi = 0; mi < 4; ++mi)
#pragma unroll
        for (int d = 0; d < 3; ++d)
#pragma unroll
            for (int ci = 0; ci < 2; ++ci) acc[mi][d][ci] = z;

    const unsigned short* aa = vf  + (size_t)(v0 + lr) * 384 + lk * 8;
    const unsigned short* bb = Awb + (size_t)(w * 32 + lr) * 384 + lk * 8;
#pragma unroll 2
    for (int kc = 0; kc < 12; ++kc) {
        short8 a[4];
#pragma unroll
        for (int mi = 0; mi < 4; ++mi)
            a[mi] = *(const short8*)(aa + mi * (16 * 384) + kc * 32);
        short8 bm[3][2];
#pragma unroll
        for (int d = 0; d < 3; ++d)
#pragma unroll
            for (int ci = 0; ci < 2; ++ci)
                bm[d][ci] = *(const short8*)(bb + (size_t)(d * 128 + ci * 16) * 384 + kc * 32);
#pragma unroll
        for (int mi = 0; mi < 4; ++mi)
#pragma unroll
            for (int d = 0; d < 3; ++d)
#pragma unroll
                for (int ci = 0; ci < 2; ++ci)
                    acc[mi][d][ci] = __builtin_amdgcn_mfma_f32_16x16x32_bf16(
                        a[mi], bm[d][ci], acc[mi][d][ci], 0, 0, 0);
    }
#pragma unroll
    for (int mi = 0; mi < 4; ++mi)
#pragma unroll
        for (int r = 0; r < 4; ++r) {
            int m = mi * 16 + lk * 4 + r;
            int v = v0 + m;
            if (v < V_) {
#pragma unroll
                for (int ci = 0; ci < 2; ++ci) {
                    int c = w * 32 + ci * 16 + lr;
                    float s = 0.f;
#pragma unroll
                    for (int d = 0; d < 3; ++d)
                        s += acc[mi][d][ci][r] * b2f(vf[(size_t)v * 384 + d * 128 + c]);
                    fb[(size_t)v * 384 + 256 + c] = f2b(tanhf(s));
                }
            }
        }
}

// ============================================================================
// k_mlp_mfma: h = relu(f @ W0^T + b0) (bf16, LDS); out = h @ W1^T + b1 + x_in
// block: 64 rows, 4 waves. GEMM1: wave w owns n in [64w,64w+64).
// GEMM2: wave w owns n in [32w, 32w+32).
// ============================================================================
__global__ __launch_bounds__(256) void k_mlp_mfma(
    const unsigned short* __restrict__ fb,
    const unsigned short* __restrict__ W0b, const float* __restrict__ b0,
    const unsigned short* __restrict__ W1b, const float* __restrict__ b1,
    const float* __restrict__ x_in, float* __restrict__ out, int b)
{
    const int v0  = blockIdx.x * 64;
    const int tid = threadIdx.x;
    const int w   = tid >> 6;
    const int lr  = tid & 15;
    const int lk  = (tid & 63) >> 4;

    __shared__ unsigned short Hs[64][264];   // 264*2=528B stride: 16B-aligned rows

    f32x4 z = {0.f, 0.f, 0.f, 0.f};
    f32x4 acc[4][4];
#pragma unroll
    for (int mi = 0; mi < 4; ++mi)
#pragma unroll
        for (int ni = 0; ni < 4; ++ni) acc[mi][ni] = z;

    const unsigned short* fa = fb  + (size_t)(v0 + lr) * 384 + lk * 8;
    const unsigned short* wb = W0b + (size_t)(w * 64 + lr) * 384 + lk * 8;
#pragma unroll 4
    for (int kc = 0; kc < 12; ++kc) {
        short8 a[4], bbf[4];
#pragma unroll
        for (int mi = 0; mi < 4; ++mi)
            a[mi] = *(const short8*)(fa + mi * (16 * 384) + kc * 32);
#pragma unroll
        for (int ni = 0; ni < 4; ++ni)
            bbf[ni] = *(const short8*)(wb + ni * (16 * 384) + kc * 32);
#pragma unroll
        for (int mi = 0; mi < 4; ++mi)
#pragma unroll
            for (int ni = 0; ni < 4; ++ni)
                acc[mi][ni] = __builtin_amdgcn_mfma_f32_16x16x32_bf16(
                    a[mi], bbf[ni], acc[mi][ni], 0, 0, 0);
    }
#pragma unroll
    for (int ni = 0; ni < 4; ++ni) {
        int n = w * 64 + ni * 16 + lr;
        float bias = b0[n];
#pragma unroll
        for (int mi = 0; mi < 4; ++mi)
#pragma unroll
            for (int r = 0; r < 4; ++r) {
                int m = mi * 16 + lk * 4 + r;
                Hs[m][n] = f2b(fmaxf(acc[mi][ni][r] + bias, 0.f));
            }
    }
    __syncthreads();

    f32x4 acc2[4][2];
#pragma unroll
    for (int mi = 0; mi < 4; ++mi)
#pragma unroll
        for (int ni = 0; ni < 2; ++ni) acc2[mi][ni] = z;

    const unsigned short* w1b = W1b + (size_t)(w * 32 + lr) * 256 + lk * 8;
#pragma unroll 4
    for (int kc = 0; kc < 8; ++kc) {
        short8 a2[4], b2[2];
#pragma unroll
        for (int mi = 0; mi < 4; ++mi)
            a2[mi] = *(const short8*)&Hs[mi * 16 + lr][kc * 32 + lk * 8];
#pragma unroll
        for (int ni = 0; ni < 2; ++ni)
            b2[ni] = *(const short8*)(w1b + ni * (16 * 256) + kc * 32);
#pragma unroll
        for (int mi = 0; mi < 4; ++mi)
#pragma unroll
            for (int ni = 0; ni < 2; ++ni)
                acc2[mi][ni] = __builtin_amdgcn_mfma_f32_16x16x32_bf16(
                    a2[mi], b2[ni], acc2[mi][ni], 0, 0, 0);
    }
#pragma unroll
    for (int ni = 0; ni < 2; ++ni) {
        int n = w * 32 + ni * 16 + lr;
        float bias = b1[n];
#pragma unroll
        for (int mi = 0; mi < 4; ++mi)
#pragma unroll
            for (int r = 0; r < 4; ++r) {
                int m = mi * 16 + lk * 4 + r;
                int v = v0 + m;
                if (v < V_) {
                    size_t o = ((size_t)b * V_ + v) * C_ + n;
                    out[o] = acc2[mi][ni][r] + bias + x_in[o];
                }
            }
    }
}

// ============================================================================
extern "C" void kernel_launch(void* const* d_in, const int* in_sizes, int n_in,
                              void* d_out, int out_size, void* d_ws, size_t ws_size,
                              hipStream_t stream)
{
    const float* x_in  = (const float*)d_in[0];
    const float* evals = (const float*)d_in[1];
    const float* evecs = (const float*)d_in[2];
    const float* mass  = (const float*)d_in[3];
    const float* gv[3] = {(const float*)d_in[4], (const float*)d_in[7], (const float*)d_in[10]};
    const int*   gr[3] = {(const int*)d_in[5],   (const int*)d_in[8],   (const int*)d_in[11]};
    const int*   gc[3] = {(const int*)d_in[6],   (const int*)d_in[9],   (const int*)d_in[12]};
    const float* dt  = (const float*)d_in[13];
    const float* Aw  = (const float*)d_in[14];
    const float* W0  = (const float*)d_in[15];
    const float* b0  = (const float*)d_in[16];
    const float* W1  = (const float*)d_in[17];
    const float* b1  = (const float*)d_in[18];
    float* out = (float*)d_out;

    float* ws_f   = (float*)d_ws;
    float* x_spec = ws_f;                               // 65536 f32
    float* spec_s = ws_f + 65536;                       // 65536 f32
    unsigned short* W0b = (unsigned short*)(ws_f + 131072);   // 98304
    unsigned short* W1b = W0b + 98304;                  // 32768
    unsigned short* Awb = W1b + 32768;                  // 147456
    unsigned short* fb  = Awb + 147456;                 // VP_*384
    unsigned short* vf  = fb + (size_t)VP_ * 384;       // VP_*384
    float* sv  = (float*)(vf + (size_t)VP_ * 384);      // 3*NNZ_
    int*   sc  = (int*)(sv + 3 * (size_t)NNZ_);         // 3*NNZ_
    int*   ptr = sc + 3 * (size_t)NNZ_;                 // 3*(V_+1)
    int*   cnt = ptr + 3 * (V_ + 1);                    // 3*V_
    int*   csum = cnt + 3 * V_;                         // 3*NCHUNK_

    hipMemsetAsync(x_spec, 0, 65536 * sizeof(float), stream);
    k_cvt_w<<<dim3(64), 256, 0, stream>>>(W0, W1, W0b, W1b);
    k_cvt_aw<<<dim3(576), 256, 0, stream>>>(Aw, Awb);

    for (int b = 0; b < B_; ++b) {
        hipMemsetAsync(cnt, 0, 3 * V_ * sizeof(int), stream);
        k_cvt_xin<<<dim3(3125), 256, 0, stream>>>(x_in, fb, b);
        k_spec<<<dim3(196, 1), 256, 0, stream>>>(evecs, mass, x_in, x_spec, b);
        k_scale<<<dim3(64), 256, 0, stream>>>(evals, dt, x_spec, spec_s, b * K_ * C_);
        k_frombasis<<<dim3(782, 1), 256, 0, stream>>>(evecs, spec_s, fb, b);
        k_count<<<dim3(3125, 3), 256, 0, stream>>>(gr[0], gr[1], gr[2], cnt, b);
        k_chunksum<<<dim3(NCHUNK_, 3), 256, 0, stream>>>(cnt, csum);
        k_chunkscan<<<dim3(1), 64, 0, stream>>>(csum, ptr);
        k_ptrwrite<<<dim3(NCHUNK_, 3), 256, 0, stream>>>(cnt, csum, ptr);
        k_fill<<<dim3(3125, 3), 256, 0, stream>>>(
            gr[0], gr[1], gr[2], gc[0], gc[1], gc[2], gv[0], gv[1], gv[2],
            ptr, cnt, sv, sc, b);
        k_gather<<<dim3(12500, 3), 256, 0, stream>>>(sv, sc, ptr, fb, vf);
        k_gf_mfma<<<dim3(782), 256, 0, stream>>>(vf, Awb, fb);
        k_mlp_mfma<<<dim3(782), 256, 0, stream>>>(fb, W0b, b0, W1b, b1, x_in, out, b);
    }
}

// Round 5
// 2243.256 us; speedup vs baseline: 8.5973x; 1.4177x over previous
//
#include <hip/hip_runtime.h>
#include <cstdint>
#include <cstddef>

#define B_   4
#define V_   50000
#define VP_  50048                       // 782*64  (fb/vf row count)
#define VPT_ 50176                       // 784*64 = 196*256 (evT/mxT v-stride)
#define K_   128
#define C_   128
#define NNZ_ 800000
#define HID_ 256

#define CHUNK_  1024
#define NCHUNK_ 49

typedef __attribute__((ext_vector_type(8))) short short8;
typedef __attribute__((ext_vector_type(4))) float f32x4;
typedef unsigned short us;

__device__ __forceinline__ us f2b(float f) {
    union { float f; unsigned u; } v; v.f = f;
    unsigned r = v.u + 0x7fffu + ((v.u >> 16) & 1u);
    return (us)(r >> 16);
}
__device__ __forceinline__ float b2f(us h) {
    union { unsigned u; float f; } v; v.u = ((unsigned)h) << 16; return v.f;
}
__device__ __forceinline__ unsigned pk(float lo, float hi) {
    return (unsigned)f2b(lo) | ((unsigned)f2b(hi) << 16);
}
__device__ __forceinline__ short8 cvt8(float4 p0, float4 p1) {
    union { unsigned u[4]; short8 s; } r;
    r.u[0] = pk(p0.x, p0.y); r.u[1] = pk(p0.z, p0.w);
    r.u[2] = pk(p1.x, p1.y); r.u[3] = pk(p1.z, p1.w);
    return r.s;
}

// ============================================================================
// weight converts (once per launch)
// ============================================================================
__global__ __launch_bounds__(256) void k_cvt_w(
    const float* __restrict__ W0, const float* __restrict__ W1,
    us* __restrict__ W0b, us* __restrict__ W1b)
{
    int t = blockIdx.x * 256 + threadIdx.x;          // 16384 threads
    const float* src; us* dst; int i8;
    if (t < 12288) { i8 = t * 8;            src = W0 + i8; dst = W0b + i8; }
    else           { i8 = (t - 12288) * 8;  src = W1 + i8; dst = W1b + i8; }
    float4 x0 = *(const float4*)src;
    float4 x1 = *(const float4*)(src + 4);
    uint4 u;
    u.x = pk(x0.x, x0.y); u.y = pk(x0.z, x0.w);
    u.z = pk(x1.x, x1.y); u.w = pk(x1.z, x1.w);
    *(uint4*)dst = u;
}

// Awb[p1*384+p2] = bf16(Aw[q(p1)*384 + q(p2)]), q(p) = 3*(p&127) + (p>>7)
__global__ __launch_bounds__(256) void k_cvt_aw(
    const float* __restrict__ Aw, us* __restrict__ Awb)
{
    int p  = blockIdx.x * 256 + threadIdx.x;         // 147456 threads
    int p1 = p / 384, p2 = p - p1 * 384;
    int q1 = 3 * (p1 & 127) + (p1 >> 7);
    int q2 = 3 * (p2 & 127) + (p2 >> 7);
    Awb[p] = f2b(Aw[q1 * 384 + q2]);
}

// ============================================================================
// k_trans_ev: evT[k][v] = bf16(evecs[b,v,k]), zero-pad v in [V_,VPT_)
// grid 784: 64 v-rows x 128 k per block, LDS-tiled transpose.
// ============================================================================
__global__ __launch_bounds__(256) void k_trans_ev(
    const float* __restrict__ evecs, us* __restrict__ evT, int b)
{
    const int v0  = blockIdx.x * 64;
    const int tid = threadIdx.x;
    __shared__ us ts[128][72];
#pragma unroll
    for (int it = 0; it < 8; ++it) {
        int f   = tid + it * 256;          // 0..2047
        int row = f >> 5;                  // 0..63
        int col = (f & 31) * 4;
        int v   = v0 + row;
        float4 e = (v < V_)
            ? *(const float4*)&evecs[((size_t)b * V_ + v) * K_ + col]
            : make_float4(0.f, 0.f, 0.f, 0.f);
        ts[col + 0][row] = f2b(e.x); ts[col + 1][row] = f2b(e.y);
        ts[col + 2][row] = f2b(e.z); ts[col + 3][row] = f2b(e.w);
    }
    __syncthreads();
    int k = tid >> 1, half = tid & 1;
#pragma unroll
    for (int q = 0; q < 4; ++q) {
        uint4 u = *(const uint4*)&ts[k][half * 32 + q * 8];
        *(uint4*)&evT[(size_t)k * VPT_ + v0 + half * 32 + q * 8] = u;
    }
}

// ============================================================================
// k_trans_mx: mxT[c][v] = bf16(x_in[b,v,c]*mass[b,v]) (zero-pad),
//             fb[v][0:128] = bf16(x_in[b,v,:])  (v < V_ only)
// ============================================================================
__global__ __launch_bounds__(256) void k_trans_mx(
    const float* __restrict__ x_in, const float* __restrict__ mass,
    us* __restrict__ mxT, us* __restrict__ fb, int b)
{
    const int v0  = blockIdx.x * 64;
    const int tid = threadIdx.x;
    __shared__ us ts[128][72];
#pragma unroll
    for (int it = 0; it < 8; ++it) {
        int f   = tid + it * 256;
        int row = f >> 5;
        int col = (f & 31) * 4;
        int v   = v0 + row;
        float4 x = make_float4(0.f, 0.f, 0.f, 0.f);
        float  m = 0.f;
        if (v < V_) {
            x = *(const float4*)&x_in[((size_t)b * V_ + v) * C_ + col];
            m = mass[b * V_ + v];
            uint2 u; u.x = pk(x.x, x.y); u.y = pk(x.z, x.w);
            *(uint2*)&fb[(size_t)v * 384 + col] = u;
        }
        ts[col + 0][row] = f2b(x.x * m); ts[col + 1][row] = f2b(x.y * m);
        ts[col + 2][row] = f2b(x.z * m); ts[col + 3][row] = f2b(x.w * m);
    }
    __syncthreads();
    int c = tid >> 1, half = tid & 1;
#pragma unroll
    for (int q = 0; q < 4; ++q) {
        uint4 u = *(const uint4*)&ts[c][half * 32 + q * 8];
        *(uint4*)&mxT[(size_t)c * VPT_ + v0 + half * 32 + q * 8] = u;
    }
}

// ============================================================================
// k_spec_mfma: x_spec[b,k,c] += sum_{v-slab} evT[k][v] * mxT[c][v]   (MFMA)
// grid 196: 256 v per block; wave w owns k in [32w,32w+32); n = full 128.
// ============================================================================
__global__ __launch_bounds__(256) void k_spec_mfma(
    const us* __restrict__ evT, const us* __restrict__ mxT,
    float* __restrict__ x_spec, int b)
{
    const int vb  = blockIdx.x * 256;
    const int tid = threadIdx.x;
    const int w   = tid >> 6;
    const int lr  = tid & 15;
    const int lk  = (tid & 63) >> 4;

    f32x4 z = {0.f, 0.f, 0.f, 0.f};
    f32x4 acc[2][8];
#pragma unroll
    for (int mi = 0; mi < 2; ++mi)
#pragma unroll
        for (int ni = 0; ni < 8; ++ni) acc[mi][ni] = z;

#pragma unroll 2
    for (int s = 0; s < 8; ++s) {
        int vo = vb + s * 32 + lk * 8;
        short8 a[2], bf[8];
#pragma unroll
        for (int mi = 0; mi < 2; ++mi)
            a[mi] = *(const short8*)&evT[(size_t)(w * 32 + mi * 16 + lr) * VPT_ + vo];
#pragma unroll
        for (int ni = 0; ni < 8; ++ni)
            bf[ni] = *(const short8*)&mxT[(size_t)(ni * 16 + lr) * VPT_ + vo];
#pragma unroll
        for (int mi = 0; mi < 2; ++mi)
#pragma unroll
            for (int ni = 0; ni < 8; ++ni)
                acc[mi][ni] = __builtin_amdgcn_mfma_f32_16x16x32_bf16(
                    a[mi], bf[ni], acc[mi][ni], 0, 0, 0);
    }
#pragma unroll
    for (int mi = 0; mi < 2; ++mi)
#pragma unroll
        for (int ni = 0; ni < 8; ++ni)
#pragma unroll
            for (int r = 0; r < 4; ++r) {
                int k = w * 32 + mi * 16 + lk * 4 + r;
                int c = ni * 16 + lr;
                atomicAdd(&x_spec[((size_t)b * K_ + k) * C_ + c], acc[mi][ni][r]);
            }
}

// ============================================================================
// k_scale2: spec_t[c][k] = bf16( exp(-evals[b,k]*max(dt[c],1e-8)) * x_spec[b,k,c] )
// ============================================================================
__global__ __launch_bounds__(256) void k_scale2(
    const float* __restrict__ evals, const float* __restrict__ dt,
    const float* __restrict__ x_spec, us* __restrict__ spec_t, int b)
{
    int i = blockIdx.x * 256 + threadIdx.x;    // < 16384
    int c = i >> 7;
    int k = i & 127;
    float t = fmaxf(dt[c], 1e-8f);
    float v = __expf(-evals[b * K_ + k] * t) * x_spec[((size_t)b * K_ + k) * C_ + c];
    spec_t[i] = f2b(v);
}

// ============================================================================
// k_frombasis_mfma: fb[v][128+c] = bf16( sum_k evecs[b,v,k] * spec_t[c][k] )
// grid 782: 64 rows; wave w owns c in [32w,32w+32). A from global fp32 (cvt).
// ============================================================================
__global__ __launch_bounds__(256) void k_frombasis_mfma(
    const float* __restrict__ evecs, const us* __restrict__ spec_t,
    us* __restrict__ fb, int b)
{
    const int v0  = blockIdx.x * 64;
    const int tid = threadIdx.x;
    const int w   = tid >> 6;
    const int lr  = tid & 15;
    const int lk  = (tid & 63) >> 4;

    f32x4 z = {0.f, 0.f, 0.f, 0.f};
    f32x4 acc[4][2];
#pragma unroll
    for (int mi = 0; mi < 4; ++mi)
#pragma unroll
        for (int ni = 0; ni < 2; ++ni) acc[mi][ni] = z;

#pragma unroll
    for (int ks = 0; ks < 4; ++ks) {
        int ko = ks * 32 + lk * 8;
        short8 a[4], bf[2];
#pragma unroll
        for (int mi = 0; mi < 4; ++mi) {
            int v = v0 + mi * 16 + lr;
            float4 p0 = make_float4(0.f, 0.f, 0.f, 0.f);
            float4 p1 = make_float4(0.f, 0.f, 0.f, 0.f);
            if (v < V_) {
                const float* src = &evecs[((size_t)b * V_ + v) * K_ + ko];
                p0 = *(const float4*)src;
                p1 = *(const float4*)(src + 4);
            }
            a[mi] = cvt8(p0, p1);
        }
#pragma unroll
        for (int ni = 0; ni < 2; ++ni)
            bf[ni] = *(const short8*)&spec_t[(size_t)(w * 32 + ni * 16 + lr) * K_ + ko];
#pragma unroll
        for (int mi = 0; mi < 4; ++mi)
#pragma unroll
            for (int ni = 0; ni < 2; ++ni)
                acc[mi][ni] = __builtin_amdgcn_mfma_f32_16x16x32_bf16(
                    a[mi], bf[ni], acc[mi][ni], 0, 0, 0);
    }
#pragma unroll
    for (int mi = 0; mi < 4; ++mi)
#pragma unroll
        for (int ni = 0; ni < 2; ++ni)
#pragma unroll
            for (int r = 0; r < 4; ++r) {
                int v = v0 + mi * 16 + lk * 4 + r;
                int c = w * 32 + ni * 16 + lr;
                if (v < V_) fb[(size_t)v * 384 + 128 + c] = f2b(acc[mi][ni][r]);
            }
}

// ============================================================================
// CSR build: count -> chunksum -> chunkscan -> ptrwrite -> fill
// ============================================================================
__global__ __launch_bounds__(256) void k_count(
    const int* __restrict__ r0, const int* __restrict__ r1,
    const int* __restrict__ r2, int* __restrict__ cnt, int b)
{
    const int d = blockIdx.y;
    const int e = blockIdx.x * 256 + threadIdx.x;
    const int* rr = (d == 0) ? r0 : (d == 1) ? r1 : r2;
    int r = rr[(size_t)b * NNZ_ + e];
    atomicAdd(&cnt[d * V_ + r], 1);
}

__global__ __launch_bounds__(256) void k_chunksum(
    const int* __restrict__ cnt, int* __restrict__ csum)
{
    const int d  = blockIdx.y;
    const int ch = blockIdx.x;
    const int tid = threadIdx.x;
    int s = 0;
#pragma unroll
    for (int j = 0; j < 4; ++j) {
        int i = ch * CHUNK_ + tid * 4 + j;
        if (i < V_) s += cnt[d * V_ + i];
    }
    __shared__ int sh[256];
    sh[tid] = s;
    __syncthreads();
    for (int off = 128; off > 0; off >>= 1) {
        if (tid < off) sh[tid] += sh[tid + off];
        __syncthreads();
    }
    if (tid == 0) csum[d * NCHUNK_ + ch] = sh[0];
}

__global__ __launch_bounds__(64) void k_chunkscan(
    int* __restrict__ csum, int* __restrict__ ptr)
{
    int d = threadIdx.x;
    if (d < 3) {
        int run = 0;
        for (int ch = 0; ch < NCHUNK_; ++ch) {
            int t = csum[d * NCHUNK_ + ch];
            csum[d * NCHUNK_ + ch] = run;
            run += t;
        }
        ptr[d * (V_ + 1) + V_] = NNZ_;
    }
}

__global__ __launch_bounds__(256) void k_ptrwrite(
    const int* __restrict__ cnt, const int* __restrict__ csum,
    int* __restrict__ ptr)
{
    const int d  = blockIdx.y;
    const int ch = blockIdx.x;
    const int tid = threadIdx.x;
    int v[4];
    int tsum = 0;
#pragma unroll
    for (int j = 0; j < 4; ++j) {
        int i = ch * CHUNK_ + tid * 4 + j;
        int x = (i < V_) ? cnt[d * V_ + i] : 0;
        v[j] = tsum;
        tsum += x;
    }
    __shared__ int sh[256];
    sh[tid] = tsum;
    __syncthreads();
    for (int off = 1; off < 256; off <<= 1) {
        int t = (tid >= off) ? sh[tid - off] : 0;
        __syncthreads();
        sh[tid] += t;
        __syncthreads();
    }
    int excl = sh[tid] - tsum;
    int base = csum[d * NCHUNK_ + ch] + excl;
#pragma unroll
    for (int j = 0; j < 4; ++j) {
        int i = ch * CHUNK_ + tid * 4 + j;
        if (i < V_) ptr[d * (V_ + 1) + i] = base + v[j];
    }
}

__global__ __launch_bounds__(256) void k_fill(
    const int* __restrict__ r0, const int* __restrict__ r1, const int* __restrict__ r2,
    const int* __restrict__ c0, const int* __restrict__ c1, const int* __restrict__ c2,
    const float* __restrict__ v0, const float* __restrict__ v1, const float* __restrict__ v2,
    const int* __restrict__ ptr, int* __restrict__ cnt,
    uint2* __restrict__ svc, int b)
{
    const int d = blockIdx.y;
    const int e = blockIdx.x * 256 + threadIdx.x;
    const int*   rr = (d == 0) ? r0 : (d == 1) ? r1 : r2;
    const int*   cc = (d == 0) ? c0 : (d == 1) ? c1 : c2;
    const float* vv = (d == 0) ? v0 : (d == 1) ? v1 : v2;
    size_t src = (size_t)b * NNZ_ + e;
    int r = rr[src];
    int k = atomicSub(&cnt[d * V_ + r], 1) - 1;
    int pos = ptr[d * (V_ + 1) + r] + k;
    uint2 ent;
    ent.x = __float_as_uint(vv[src]);
    ent.y = (unsigned)cc[src];
    svc[(size_t)d * NNZ_ + pos] = ent;
}

// ============================================================================
// k_gather: vf[r][d*128+c] = bf16( sum_e val_e * x_diffuse_bf16[col_e][c] )
// one wave per row, 2 bf16/lane; 4-way unrolled for memory-level parallelism.
// ============================================================================
__global__ __launch_bounds__(256) void k_gather(
    const uint2* __restrict__ svc, const int* __restrict__ ptr,
    const us* __restrict__ fb, us* __restrict__ vf)
{
    const int d    = blockIdx.y;
    const int w    = threadIdx.x >> 6;
    const int lane = threadIdx.x & 63;
    const int r    = blockIdx.x * 4 + w;
    int beg = ptr[d * (V_ + 1) + r];
    int end = ptr[d * (V_ + 1) + r + 1];
    const uint2* base = svc + (size_t)d * NNZ_;
    const int lo2 = lane * 2;

    float a0x = 0.f, a0y = 0.f, a1x = 0.f, a1y = 0.f;
    float a2x = 0.f, a2y = 0.f, a3x = 0.f, a3y = 0.f;
    int i = beg;
    for (; i + 4 <= end; i += 4) {
        uint2 e0 = base[i], e1 = base[i + 1], e2 = base[i + 2], e3 = base[i + 3];
        unsigned u0 = *(const unsigned*)&fb[(size_t)e0.y * 384 + 128 + lo2];
        unsigned u1 = *(const unsigned*)&fb[(size_t)e1.y * 384 + 128 + lo2];
        unsigned u2 = *(const unsigned*)&fb[(size_t)e2.y * 384 + 128 + lo2];
        unsigned u3 = *(const unsigned*)&fb[(size_t)e3.y * 384 + 128 + lo2];
        float v0f = __uint_as_float(e0.x), v1f = __uint_as_float(e1.x);
        float v2f = __uint_as_float(e2.x), v3f = __uint_as_float(e3.x);
        a0x += v0f * b2f((us)(u0 & 0xffffu)); a0y += v0f * b2f((us)(u0 >> 16));
        a1x += v1f * b2f((us)(u1 & 0xffffu)); a1y += v1f * b2f((us)(u1 >> 16));
        a2x += v2f * b2f((us)(u2 & 0xffffu)); a2y += v2f * b2f((us)(u2 >> 16));
        a3x += v3f * b2f((us)(u3 & 0xffffu)); a3y += v3f * b2f((us)(u3 >> 16));
    }
    for (; i < end; ++i) {
        uint2 e0 = base[i];
        unsigned u0 = *(const unsigned*)&fb[(size_t)e0.y * 384 + 128 + lo2];
        float v0f = __uint_as_float(e0.x);
        a0x += v0f * b2f((us)(u0 & 0xffffu)); a0y += v0f * b2f((us)(u0 >> 16));
    }
    float ax = (a0x + a1x) + (a2x + a3x);
    float ay = (a0y + a1y) + (a2y + a3y);
    *(unsigned*)&vf[(size_t)r * 384 + d * 128 + lo2] = pk(ax, ay);
}

// ============================================================================
// k_gf_mfma: Av' = vf @ Awb^T (MFMA bf16), then
// f[v][256+c] = bf16(tanh(sum_d Av'[v][d*128+c] * vf[v][d*128+c]))
// ============================================================================
__global__ __launch_bounds__(256) void k_gf_mfma(
    const us* __restrict__ vf, const us* __restrict__ Awb,
    us* __restrict__ fb)
{
    const int v0  = blockIdx.x * 64;
    const int tid = threadIdx.x;
    const int w   = tid >> 6;
    const int lr  = tid & 15;
    const int lk  = (tid & 63) >> 4;

    f32x4 z = {0.f, 0.f, 0.f, 0.f};
    f32x4 acc[4][3][2];
#pragma unroll
    for (int mi = 0; mi < 4; ++mi)
#pragma unroll
        for (int d = 0; d < 3; ++d)
#pragma unroll
            for (int ci = 0; ci < 2; ++ci) acc[mi][d][ci] = z;

    const us* aa = vf  + (size_t)(v0 + lr) * 384 + lk * 8;
    const us* bb = Awb + (size_t)(w * 32 + lr) * 384 + lk * 8;
#pragma unroll 2
    for (int kc = 0; kc < 12; ++kc) {
        short8 a[4];
#pragma unroll
        for (int mi = 0; mi < 4; ++mi)
            a[mi] = *(const short8*)(aa + mi * (16 * 384) + kc * 32);
        short8 bm[3][2];
#pragma unroll
        for (int d = 0; d < 3; ++d)
#pragma unroll
            for (int ci = 0; ci < 2; ++ci)
                bm[d][ci] = *(const short8*)(bb + (size_t)(d * 128 + ci * 16) * 384 + kc * 32);
#pragma unroll
        for (int mi = 0; mi < 4; ++mi)
#pragma unroll
            for (int d = 0; d < 3; ++d)
#pragma unroll
                for (int ci = 0; ci < 2; ++ci)
                    acc[mi][d][ci] = __builtin_amdgcn_mfma_f32_16x16x32_bf16(
                        a[mi], bm[d][ci], acc[mi][d][ci], 0, 0, 0);
    }
#pragma unroll
    for (int mi = 0; mi < 4; ++mi)
#pragma unroll
        for (int r = 0; r < 4; ++r) {
            int m = mi * 16 + lk * 4 + r;
            int v = v0 + m;
            if (v < V_) {
#pragma unroll
                for (int ci = 0; ci < 2; ++ci) {
                    int c = w * 32 + ci * 16 + lr;
                    float s = 0.f;
#pragma unroll
                    for (int d = 0; d < 3; ++d)
                        s += acc[mi][d][ci][r] * b2f(vf[(size_t)v * 384 + d * 128 + c]);
                    fb[(size_t)v * 384 + 256 + c] = f2b(tanhf(s));
                }
            }
        }
}

// ============================================================================
// k_mlp_mfma: h = relu(f @ W0^T + b0) (bf16, LDS); out = h @ W1^T + b1 + x_in
// ============================================================================
__global__ __launch_bounds__(256) void k_mlp_mfma(
    const us* __restrict__ fb,
    const us* __restrict__ W0b, const float* __restrict__ b0,
    const us* __restrict__ W1b, const float* __restrict__ b1,
    const float* __restrict__ x_in, float* __restrict__ out, int b)
{
    const int v0  = blockIdx.x * 64;
    const int tid = threadIdx.x;
    const int w   = tid >> 6;
    const int lr  = tid & 15;
    const int lk  = (tid & 63) >> 4;

    __shared__ us Hs[64][264];

    f32x4 z = {0.f, 0.f, 0.f, 0.f};
    f32x4 acc[4][4];
#pragma unroll
    for (int mi = 0; mi < 4; ++mi)
#pragma unroll
        for (int ni = 0; ni < 4; ++ni) acc[mi][ni] = z;

    const us* fa = fb  + (size_t)(v0 + lr) * 384 + lk * 8;
    const us* wb = W0b + (size_t)(w * 64 + lr) * 384 + lk * 8;
#pragma unroll 4
    for (int kc = 0; kc < 12; ++kc) {
        short8 a[4], bbf[4];
#pragma unroll
        for (int mi = 0; mi < 4; ++mi)
            a[mi] = *(const short8*)(fa + mi * (16 * 384) + kc * 32);
#pragma unroll
        for (int ni = 0; ni < 4; ++ni)
            bbf[ni] = *(const short8*)(wb + ni * (16 * 384) + kc * 32);
#pragma unroll
        for (int mi = 0; mi < 4; ++mi)
#pragma unroll
            for (int ni = 0; ni < 4; ++ni)
                acc[mi][ni] = __builtin_amdgcn_mfma_f32_16x16x32_bf16(
                    a[mi], bbf[ni], acc[mi][ni], 0, 0, 0);
    }
#pragma unroll
    for (int ni = 0; ni < 4; ++ni) {
        int n = w * 64 + ni * 16 + lr;
        float bias = b0[n];
#pragma unroll
        for (int mi = 0; mi < 4; ++mi)
#pragma unroll
            for (int r = 0; r < 4; ++r) {
                int m = mi * 16 + lk * 4 + r;
                Hs[m][n] = f2b(fmaxf(acc[mi][ni][r] + bias, 0.f));
            }
    }
    __syncthreads();

    f32x4 acc2[4][2];
#pragma unroll
    for (int mi = 0; mi < 4; ++mi)
#pragma unroll
        for (int ni = 0; ni < 2; ++ni) acc2[mi][ni] = z;

    const us* w1b = W1b + (size_t)(w * 32 + lr) * 256 + lk * 8;
#pragma unroll 4
    for (int kc = 0; kc < 8; ++kc) {
        short8 a2[4], b2[2];
#pragma unroll
        for (int mi = 0; mi < 4; ++mi)
            a2[mi] = *(const short8*)&Hs[mi * 16 + lr][kc * 32 + lk * 8];
#pragma unroll
        for (int ni = 0; ni < 2; ++ni)
            b2[ni] = *(const short8*)(w1b + ni * (16 * 256) + kc * 32);
#pragma unroll
        for (int mi = 0; mi < 4; ++mi)
#pragma unroll
            for (int ni = 0; ni < 2; ++ni)
                acc2[mi][ni] = __builtin_amdgcn_mfma_f32_16x16x32_bf16(
                    a2[mi], b2[ni], acc2[mi][ni], 0, 0, 0);
    }
#pragma unroll
    for (int ni = 0; ni < 2; ++ni) {
        int n = w * 32 + ni * 16 + lr;
        float bias = b1[n];
#pragma unroll
        for (int mi = 0; mi < 4; ++mi)
#pragma unroll
            for (int r = 0; r < 4; ++r) {
                int m = mi * 16 + lk * 4 + r;
                int v = v0 + m;
                if (v < V_) {
                    size_t o = ((size_t)b * V_ + v) * C_ + n;
                    out[o] = acc2[mi][ni][r] + bias + x_in[o];
                }
            }
    }
}

// ============================================================================
extern "C" void kernel_launch(void* const* d_in, const int* in_sizes, int n_in,
                              void* d_out, int out_size, void* d_ws, size_t ws_size,
                              hipStream_t stream)
{
    const float* x_in  = (const float*)d_in[0];
    const float* evals = (const float*)d_in[1];
    const float* evecs = (const float*)d_in[2];
    const float* mass  = (const float*)d_in[3];
    const float* gv[3] = {(const float*)d_in[4], (const float*)d_in[7], (const float*)d_in[10]};
    const int*   gr[3] = {(const int*)d_in[5],   (const int*)d_in[8],   (const int*)d_in[11]};
    const int*   gc[3] = {(const int*)d_in[6],   (const int*)d_in[9],   (const int*)d_in[12]};
    const float* dt  = (const float*)d_in[13];
    const float* Aw  = (const float*)d_in[14];
    const float* W0  = (const float*)d_in[15];
    const float* b0  = (const float*)d_in[16];
    const float* W1  = (const float*)d_in[17];
    const float* b1  = (const float*)d_in[18];
    float* out = (float*)d_out;

    // ---- workspace layout (≈124 MB) ----
    float* x_spec = (float*)d_ws;                            // 65536 f32
    us* spec_t = (us*)(x_spec + 65536);                      // 16384
    us* W0b    = spec_t + 16384;                             // 98304
    us* W1b    = W0b + 98304;                                // 32768
    us* Awb    = W1b + 32768;                                // 147456
    us* fb     = Awb + 147456;                               // VP_*384
    us* vf     = fb + (size_t)VP_ * 384;                     // VP_*384
    us* evT    = vf + (size_t)VP_ * 384;                     // 128*VPT_
    us* mxT    = evT + (size_t)128 * VPT_;                   // 128*VPT_
    uint2* svc = (uint2*)(mxT + (size_t)128 * VPT_);         // 3*NNZ_ uint2
    int* ptr   = (int*)(svc + 3 * (size_t)NNZ_);             // 3*(V_+1)
    int* cnt   = ptr + 3 * (V_ + 1);                         // 3*V_
    int* csum  = cnt + 3 * V_;                               // 3*NCHUNK_

    hipMemsetAsync(x_spec, 0, 65536 * sizeof(float), stream);
    k_cvt_w<<<dim3(64), 256, 0, stream>>>(W0, W1, W0b, W1b);
    k_cvt_aw<<<dim3(576), 256, 0, stream>>>(Aw, Awb);

    for (int b = 0; b < B_; ++b) {
        hipMemsetAsync(cnt, 0, 3 * V_ * sizeof(int), stream);
        k_trans_mx<<<dim3(784), 256, 0, stream>>>(x_in, mass, mxT, fb, b);
        k_trans_ev<<<dim3(784), 256, 0, stream>>>(evecs, evT, b);
        k_spec_mfma<<<dim3(196), 256, 0, stream>>>(evT, mxT, x_spec, b);
        k_scale2<<<dim3(64), 256, 0, stream>>>(evals, dt, x_spec, spec_t, b);
        k_frombasis_mfma<<<dim3(782), 256, 0, stream>>>(evecs, spec_t, fb, b);
        k_count<<<dim3(3125, 3), 256, 0, stream>>>(gr[0], gr[1], gr[2], cnt, b);
        k_chunksum<<<dim3(NCHUNK_, 3), 256, 0, stream>>>(cnt, csum);
        k_chunkscan<<<dim3(1), 64, 0, stream>>>(csum, ptr);
        k_ptrwrite<<<dim3(NCHUNK_, 3), 256, 0, stream>>>(cnt, csum, ptr);
        k_fill<<<dim3(3125, 3), 256, 0, stream>>>(
            gr[0], gr[1], gr[2], gc[0], gc[1], gc[2], gv[0], gv[1], gv[2],
            ptr, cnt, svc, b);
        k_gather<<<dim3(12500, 3), 256, 0, stream>>>(svc, ptr, fb, vf);
        k_gf_mfma<<<dim3(782), 256, 0, stream>>>(vf, Awb, fb);
        k_mlp_mfma<<<dim3(782), 256, 0, stream>>>(fb, W0b, b0, W1b, b1, x_in, out, b);
    }
}

// Round 6
// 2239.896 us; speedup vs baseline: 8.6102x; 1.0015x over previous
//
#include <hip/hip_runtime.h>
#include <cstdint>
#include <cstddef>

#define B_   4
#define V_   50000
#define VP_  50048                       // 782*64  (fb/vf row count)
#define VPT_ 50176                       // 784*64 = 196*256 (evT/mxT v-stride)
#define K_   128
#define C_   128
#define NNZ_ 800000
#define HID_ 256

#define CHUNK_  1024
#define NCHUNK_ 49
#define NSLICE_ 7                        // row slices: r>>13, 0..6

typedef __attribute__((ext_vector_type(8))) short short8;
typedef __attribute__((ext_vector_type(4))) float f32x4;
typedef unsigned short us;

__device__ __forceinline__ us f2b(float f) {
    union { float f; unsigned u; } v; v.f = f;
    unsigned r = v.u + 0x7fffu + ((v.u >> 16) & 1u);
    return (us)(r >> 16);
}
__device__ __forceinline__ float b2f(us h) {
    union { unsigned u; float f; } v; v.u = ((unsigned)h) << 16; return v.f;
}
__device__ __forceinline__ unsigned pk(float lo, float hi) {
    return (unsigned)f2b(lo) | ((unsigned)f2b(hi) << 16);
}
__device__ __forceinline__ short8 cvt8(float4 p0, float4 p1) {
    union { unsigned u[4]; short8 s; } r;
    r.u[0] = pk(p0.x, p0.y); r.u[1] = pk(p0.z, p0.w);
    r.u[2] = pk(p1.x, p1.y); r.u[3] = pk(p1.z, p1.w);
    return r.s;
}

// ============================================================================
// k_cvt_all: W0/W1 bf16 convert + Aw permuted bf16 convert (one dispatch)
// ============================================================================
__global__ __launch_bounds__(256) void k_cvt_all(
    const float* __restrict__ W0, const float* __restrict__ W1,
    const float* __restrict__ Aw,
    us* __restrict__ W0b, us* __restrict__ W1b, us* __restrict__ Awb)
{
    int t = blockIdx.x * 256 + threadIdx.x;          // 163840 threads total
    if (t < 16384) {
        const float* src; us* dst; int i8;
        if (t < 12288) { i8 = t * 8;            src = W0 + i8; dst = W0b + i8; }
        else           { i8 = (t - 12288) * 8;  src = W1 + i8; dst = W1b + i8; }
        float4 x0 = *(const float4*)src;
        float4 x1 = *(const float4*)(src + 4);
        uint4 u;
        u.x = pk(x0.x, x0.y); u.y = pk(x0.z, x0.w);
        u.z = pk(x1.x, x1.y); u.w = pk(x1.z, x1.w);
        *(uint4*)dst = u;
    } else {
        int p  = t - 16384;                          // < 147456
        int p1 = p / 384, p2 = p - p1 * 384;
        int q1 = 3 * (p1 & 127) + (p1 >> 7);
        int q2 = 3 * (p2 & 127) + (p2 >> 7);
        Awb[p] = f2b(Aw[q1 * 384 + q2]);
    }
}

// ============================================================================
// k_trans: fused
//   mxT[c][v] = bf16(x_in[b,v,c]*mass[b,v]);  fb[v][0:128] = bf16(x_in[b,v,:])
//   evT[k][v] = bf16(evecs[b,v,k])
// grid 784: 64 v-rows per block, LDS-tiled transpose, two phases.
// ============================================================================
__global__ __launch_bounds__(256) void k_trans(
    const float* __restrict__ x_in, const float* __restrict__ mass,
    const float* __restrict__ evecs,
    us* __restrict__ mxT, us* __restrict__ evT, us* __restrict__ fb, int b)
{
    const int v0  = blockIdx.x * 64;
    const int tid = threadIdx.x;
    __shared__ us ts[128][72];

    // ---- phase 1: mass*x_in transpose (+ fb[0:128] write) ----
#pragma unroll
    for (int it = 0; it < 8; ++it) {
        int f   = tid + it * 256;
        int row = f >> 5;
        int col = (f & 31) * 4;
        int v   = v0 + row;
        float4 x = make_float4(0.f, 0.f, 0.f, 0.f);
        float  m = 0.f;
        if (v < V_) {
            x = *(const float4*)&x_in[((size_t)b * V_ + v) * C_ + col];
            m = mass[b * V_ + v];
            uint2 u; u.x = pk(x.x, x.y); u.y = pk(x.z, x.w);
            *(uint2*)&fb[(size_t)v * 384 + col] = u;
        }
        ts[col + 0][row] = f2b(x.x * m); ts[col + 1][row] = f2b(x.y * m);
        ts[col + 2][row] = f2b(x.z * m); ts[col + 3][row] = f2b(x.w * m);
    }
    __syncthreads();
    {
        int c = tid >> 1, half = tid & 1;
#pragma unroll
        for (int q = 0; q < 4; ++q) {
            uint4 u = *(const uint4*)&ts[c][half * 32 + q * 8];
            *(uint4*)&mxT[(size_t)c * VPT_ + v0 + half * 32 + q * 8] = u;
        }
    }
    __syncthreads();   // protect ts before restage

    // ---- phase 2: evecs transpose ----
#pragma unroll
    for (int it = 0; it < 8; ++it) {
        int f   = tid + it * 256;
        int row = f >> 5;
        int col = (f & 31) * 4;
        int v   = v0 + row;
        float4 e = (v < V_)
            ? *(const float4*)&evecs[((size_t)b * V_ + v) * K_ + col]
            : make_float4(0.f, 0.f, 0.f, 0.f);
        ts[col + 0][row] = f2b(e.x); ts[col + 1][row] = f2b(e.y);
        ts[col + 2][row] = f2b(e.z); ts[col + 3][row] = f2b(e.w);
    }
    __syncthreads();
    {
        int k = tid >> 1, half = tid & 1;
#pragma unroll
        for (int q = 0; q < 4; ++q) {
            uint4 u = *(const uint4*)&ts[k][half * 32 + q * 8];
            *(uint4*)&evT[(size_t)k * VPT_ + v0 + half * 32 + q * 8] = u;
        }
    }
}

// ============================================================================
// k_spec_mfma: x_spec[b,k,c] += sum_{v-slab} evT[k][v] * mxT[c][v]   (MFMA)
// ============================================================================
__global__ __launch_bounds__(256) void k_spec_mfma(
    const us* __restrict__ evT, const us* __restrict__ mxT,
    float* __restrict__ x_spec, int b)
{
    const int vb  = blockIdx.x * 256;
    const int tid = threadIdx.x;
    const int w   = tid >> 6;
    const int lr  = tid & 15;
    const int lk  = (tid & 63) >> 4;

    f32x4 z = {0.f, 0.f, 0.f, 0.f};
    f32x4 acc[2][8];
#pragma unroll
    for (int mi = 0; mi < 2; ++mi)
#pragma unroll
        for (int ni = 0; ni < 8; ++ni) acc[mi][ni] = z;

#pragma unroll 2
    for (int s = 0; s < 8; ++s) {
        int vo = vb + s * 32 + lk * 8;
        short8 a[2], bf[8];
#pragma unroll
        for (int mi = 0; mi < 2; ++mi)
            a[mi] = *(const short8*)&evT[(size_t)(w * 32 + mi * 16 + lr) * VPT_ + vo];
#pragma unroll
        for (int ni = 0; ni < 8; ++ni)
            bf[ni] = *(const short8*)&mxT[(size_t)(ni * 16 + lr) * VPT_ + vo];
#pragma unroll
        for (int mi = 0; mi < 2; ++mi)
#pragma unroll
            for (int ni = 0; ni < 8; ++ni)
                acc[mi][ni] = __builtin_amdgcn_mfma_f32_16x16x32_bf16(
                    a[mi], bf[ni], acc[mi][ni], 0, 0, 0);
    }
#pragma unroll
    for (int mi = 0; mi < 2; ++mi)
#pragma unroll
        for (int ni = 0; ni < 8; ++ni)
#pragma unroll
            for (int r = 0; r < 4; ++r) {
                int k = w * 32 + mi * 16 + lk * 4 + r;
                int c = ni * 16 + lr;
                atomicAdd(&x_spec[((size_t)b * K_ + k) * C_ + c], acc[mi][ni][r]);
            }
}

// ============================================================================
// k_scale2: spec_t[c][k] = bf16( exp(-evals[b,k]*max(dt[c],1e-8)) * x_spec[b,k,c] )
// ============================================================================
__global__ __launch_bounds__(256) void k_scale2(
    const float* __restrict__ evals, const float* __restrict__ dt,
    const float* __restrict__ x_spec, us* __restrict__ spec_t, int b)
{
    int i = blockIdx.x * 256 + threadIdx.x;    // < 16384
    int c = i >> 7;
    int k = i & 127;
    float t = fmaxf(dt[c], 1e-8f);
    float v = __expf(-evals[b * K_ + k] * t) * x_spec[((size_t)b * K_ + k) * C_ + c];
    spec_t[i] = f2b(v);
}

// ============================================================================
// k_frombasis_mfma: fb[v][128+c] = bf16( sum_k evecs[b,v,k] * spec_t[c][k] )
// ============================================================================
__global__ __launch_bounds__(256) void k_frombasis_mfma(
    const float* __restrict__ evecs, const us* __restrict__ spec_t,
    us* __restrict__ fb, int b)
{
    const int v0  = blockIdx.x * 64;
    const int tid = threadIdx.x;
    const int w   = tid >> 6;
    const int lr  = tid & 15;
    const int lk  = (tid & 63) >> 4;

    f32x4 z = {0.f, 0.f, 0.f, 0.f};
    f32x4 acc[4][2];
#pragma unroll
    for (int mi = 0; mi < 4; ++mi)
#pragma unroll
        for (int ni = 0; ni < 2; ++ni) acc[mi][ni] = z;

#pragma unroll
    for (int ks = 0; ks < 4; ++ks) {
        int ko = ks * 32 + lk * 8;
        short8 a[4], bf[2];
#pragma unroll
        for (int mi = 0; mi < 4; ++mi) {
            int v = v0 + mi * 16 + lr;
            float4 p0 = make_float4(0.f, 0.f, 0.f, 0.f);
            float4 p1 = make_float4(0.f, 0.f, 0.f, 0.f);
            if (v < V_) {
                const float* src = &evecs[((size_t)b * V_ + v) * K_ + ko];
                p0 = *(const float4*)src;
                p1 = *(const float4*)(src + 4);
            }
            a[mi] = cvt8(p0, p1);
        }
#pragma unroll
        for (int ni = 0; ni < 2; ++ni)
            bf[ni] = *(const short8*)&spec_t[(size_t)(w * 32 + ni * 16 + lr) * K_ + ko];
#pragma unroll
        for (int mi = 0; mi < 4; ++mi)
#pragma unroll
            for (int ni = 0; ni < 2; ++ni)
                acc[mi][ni] = __builtin_amdgcn_mfma_f32_16x16x32_bf16(
                    a[mi], bf[ni], acc[mi][ni], 0, 0, 0);
    }
#pragma unroll
    for (int mi = 0; mi < 4; ++mi)
#pragma unroll
        for (int ni = 0; ni < 2; ++ni)
#pragma unroll
            for (int r = 0; r < 4; ++r) {
                int v = v0 + mi * 16 + lk * 4 + r;
                int c = w * 32 + ni * 16 + lr;
                if (v < V_) fb[(size_t)v * 384 + 128 + c] = f2b(acc[mi][ni][r]);
            }
}

// ============================================================================
// CSR build: count -> chunksum -> chunkscan -> ptrwrite -> fill(sliced)
// ============================================================================
__global__ __launch_bounds__(256) void k_count(
    const int* __restrict__ r0, const int* __restrict__ r1,
    const int* __restrict__ r2, int* __restrict__ cnt, int b)
{
    const int d = blockIdx.y;
    const int e = blockIdx.x * 256 + threadIdx.x;
    const int* rr = (d == 0) ? r0 : (d == 1) ? r1 : r2;
    int r = rr[(size_t)b * NNZ_ + e];
    atomicAdd(&cnt[d * V_ + r], 1);
}

__global__ __launch_bounds__(256) void k_chunksum(
    const int* __restrict__ cnt, int* __restrict__ csum)
{
    const int d  = blockIdx.y;
    const int ch = blockIdx.x;
    const int tid = threadIdx.x;
    int s = 0;
#pragma unroll
    for (int j = 0; j < 4; ++j) {
        int i = ch * CHUNK_ + tid * 4 + j;
        if (i < V_) s += cnt[d * V_ + i];
    }
    __shared__ int sh[256];
    sh[tid] = s;
    __syncthreads();
    for (int off = 128; off > 0; off >>= 1) {
        if (tid < off) sh[tid] += sh[tid + off];
        __syncthreads();
    }
    if (tid == 0) csum[d * NCHUNK_ + ch] = sh[0];
}

__global__ __launch_bounds__(64) void k_chunkscan(
    int* __restrict__ csum, int* __restrict__ ptr)
{
    int d = threadIdx.x;
    if (d < 3) {
        int run = 0;
        for (int ch = 0; ch < NCHUNK_; ++ch) {
            int t = csum[d * NCHUNK_ + ch];
            csum[d * NCHUNK_ + ch] = run;
            run += t;
        }
        ptr[d * (V_ + 1) + V_] = NNZ_;
    }
}

__global__ __launch_bounds__(256) void k_ptrwrite(
    const int* __restrict__ cnt, const int* __restrict__ csum,
    int* __restrict__ ptr)
{
    const int d  = blockIdx.y;
    const int ch = blockIdx.x;
    const int tid = threadIdx.x;
    int v[4];
    int tsum = 0;
#pragma unroll
    for (int j = 0; j < 4; ++j) {
        int i = ch * CHUNK_ + tid * 4 + j;
        int x = (i < V_) ? cnt[d * V_ + i] : 0;
        v[j] = tsum;
        tsum += x;
    }
    __shared__ int sh[256];
    sh[tid] = tsum;
    __syncthreads();
    for (int off = 1; off < 256; off <<= 1) {
        int t = (tid >= off) ? sh[tid - off] : 0;
        __syncthreads();
        sh[tid] += t;
        __syncthreads();
    }
    int excl = sh[tid] - tsum;
    int base = csum[d * NCHUNK_ + ch] + excl;
#pragma unroll
    for (int j = 0; j < 4; ++j) {
        int i = ch * CHUNK_ + tid * 4 + j;
        if (i < V_) ptr[d * (V_ + 1) + i] = base + v[j];
    }
}

// sliced fill: blockIdx.z = row slice (r>>13); active write region stays
// L2-resident so 8B scatter stores coalesce into full lines before writeback.
__global__ __launch_bounds__(256) void k_fill(
    const int* __restrict__ r0, const int* __restrict__ r1, const int* __restrict__ r2,
    const int* __restrict__ c0, const int* __restrict__ c1, const int* __restrict__ c2,
    const float* __restrict__ v0, const float* __restrict__ v1, const float* __restrict__ v2,
    const int* __restrict__ ptr, int* __restrict__ cnt,
    uint2* __restrict__ svc, int b)
{
    const int d = blockIdx.y;
    const int s = blockIdx.z;
    const int e = blockIdx.x * 256 + threadIdx.x;
    const int*   rr = (d == 0) ? r0 : (d == 1) ? r1 : r2;
    size_t src = (size_t)b * NNZ_ + e;
    int r = rr[src];
    if ((r >> 13) != s) return;
    const int*   cc = (d == 0) ? c0 : (d == 1) ? c1 : c2;
    const float* vv = (d == 0) ? v0 : (d == 1) ? v1 : v2;
    int k = atomicSub(&cnt[d * V_ + r], 1) - 1;
    int pos = ptr[d * (V_ + 1) + r] + k;
    uint2 ent;
    ent.x = __float_as_uint(vv[src]);
    ent.y = (unsigned)cc[src];
    svc[(size_t)d * NNZ_ + pos] = ent;
}

// ============================================================================
// k_gather: vf[r][d*128+c] = bf16( sum_e val_e * x_diffuse_bf16[col_e][c] )
// one wave per row, 2 bf16/lane; 8-way unrolled for memory-level parallelism.
// ============================================================================
__global__ __launch_bounds__(256) void k_gather(
    const uint2* __restrict__ svc, const int* __restrict__ ptr,
    const us* __restrict__ fb, us* __restrict__ vf)
{
    const int d    = blockIdx.y;
    const int w    = threadIdx.x >> 6;
    const int lane = threadIdx.x & 63;
    const int r    = blockIdx.x * 4 + w;
    int beg = ptr[d * (V_ + 1) + r];
    int end = ptr[d * (V_ + 1) + r + 1];
    const uint2* base = svc + (size_t)d * NNZ_;
    const int lo2 = lane * 2;

    float ax[8], ay[8];
#pragma unroll
    for (int j = 0; j < 8; ++j) { ax[j] = 0.f; ay[j] = 0.f; }

    int i = beg;
    for (; i + 8 <= end; i += 8) {
        uint2 e[8];
#pragma unroll
        for (int j = 0; j < 8; ++j) e[j] = base[i + j];
        unsigned u[8];
#pragma unroll
        for (int j = 0; j < 8; ++j)
            u[j] = *(const unsigned*)&fb[(size_t)e[j].y * 384 + 128 + lo2];
#pragma unroll
        for (int j = 0; j < 8; ++j) {
            float v = __uint_as_float(e[j].x);
            ax[j] += v * b2f((us)(u[j] & 0xffffu));
            ay[j] += v * b2f((us)(u[j] >> 16));
        }
    }
    for (; i < end; ++i) {
        uint2 e0 = base[i];
        unsigned u0 = *(const unsigned*)&fb[(size_t)e0.y * 384 + 128 + lo2];
        float v = __uint_as_float(e0.x);
        ax[0] += v * b2f((us)(u0 & 0xffffu));
        ay[0] += v * b2f((us)(u0 >> 16));
    }
    float sx = ((ax[0] + ax[1]) + (ax[2] + ax[3])) + ((ax[4] + ax[5]) + (ax[6] + ax[7]));
    float sy = ((ay[0] + ay[1]) + (ay[2] + ay[3])) + ((ay[4] + ay[5]) + (ay[6] + ay[7]));
    *(unsigned*)&vf[(size_t)r * 384 + d * 128 + lo2] = pk(sx, sy);
}

// ============================================================================
// k_gf_mfma: Av' = vf @ Awb^T (MFMA bf16), then
// f[v][256+c] = bf16(tanh(sum_d Av'[v][d*128+c] * vf[v][d*128+c]))
// ============================================================================
__global__ __launch_bounds__(256) void k_gf_mfma(
    const us* __restrict__ vf, const us* __restrict__ Awb,
    us* __restrict__ fb)
{
    const int v0  = blockIdx.x * 64;
    const int tid = threadIdx.x;
    const int w   = tid >> 6;
    const int lr  = tid & 15;
    const int lk  = (tid & 63) >> 4;

    f32x4 z = {0.f, 0.f, 0.f, 0.f};
    f32x4 acc[4][3][2];
#pragma unroll
    for (int mi = 0; mi < 4; ++mi)
#pragma unroll
        for (int d = 0; d < 3; ++d)
#pragma unroll
            for (int ci = 0; ci < 2; ++ci) acc[mi][d][ci] = z;

    const us* aa = vf  + (size_t)(v0 + lr) * 384 + lk * 8;
    const us* bb = Awb + (size_t)(w * 32 + lr) * 384 + lk * 8;
#pragma unroll 2
    for (int kc = 0; kc < 12; ++kc) {
        short8 a[4];
#pragma unroll
        for (int mi = 0; mi < 4; ++mi)
            a[mi] = *(const short8*)(aa + mi * (16 * 384) + kc * 32);
        short8 bm[3][2];
#pragma unroll
        for (int d = 0; d < 3; ++d)
#pragma unroll
            for (int ci = 0; ci < 2; ++ci)
                bm[d][ci] = *(const short8*)(bb + (size_t)(d * 128 + ci * 16) * 384 + kc * 32);
#pragma unroll
        for (int mi = 0; mi < 4; ++mi)
#pragma unroll
            for (int d = 0; d < 3; ++d)
#pragma unroll
                for (int ci = 0; ci < 2; ++ci)
                    acc[mi][d][ci] = __builtin_amdgcn_mfma_f32_16x16x32_bf16(
                        a[mi], bm[d][ci], acc[mi][d][ci], 0, 0, 0);
    }
#pragma unroll
    for (int mi = 0; mi < 4; ++mi)
#pragma unroll
        for (int r = 0; r < 4; ++r) {
            int m = mi * 16 + lk * 4 + r;
            int v = v0 + m;
            if (v < V_) {
#pragma unroll
                for (int ci = 0; ci < 2; ++ci) {
                    int c = w * 32 + ci * 16 + lr;
                    float s = 0.f;
#pragma unroll
                    for (int d = 0; d < 3; ++d)
                        s += acc[mi][d][ci][r] * b2f(vf[(size_t)v * 384 + d * 128 + c]);
                    fb[(size_t)v * 384 + 256 + c] = f2b(tanhf(s));
                }
            }
        }
}

// ============================================================================
// k_mlp_mfma: h = relu(f @ W0^T + b0) (bf16, LDS); out = h @ W1^T + b1 + x_in
// ============================================================================
__global__ __launch_bounds__(256) void k_mlp_mfma(
    const us* __restrict__ fb,
    const us* __restrict__ W0b, const float* __restrict__ b0,
    const us* __restrict__ W1b, const float* __restrict__ b1,
    const float* __restrict__ x_in, float* __restrict__ out, int b)
{
    const int v0  = blockIdx.x * 64;
    const int tid = threadIdx.x;
    const int w   = tid >> 6;
    const int lr  = tid & 15;
    const int lk  = (tid & 63) >> 4;

    __shared__ us Hs[64][264];

    f32x4 z = {0.f, 0.f, 0.f, 0.f};
    f32x4 acc[4][4];
#pragma unroll
    for (int mi = 0; mi < 4; ++mi)
#pragma unroll
        for (int ni = 0; ni < 4; ++ni) acc[mi][ni] = z;

    const us* fa = fb  + (size_t)(v0 + lr) * 384 + lk * 8;
    const us* wb = W0b + (size_t)(w * 64 + lr) * 384 + lk * 8;
#pragma unroll 4
    for (int kc = 0; kc < 12; ++kc) {
        short8 a[4], bbf[4];
#pragma unroll
        for (int mi = 0; mi < 4; ++mi)
            a[mi] = *(const short8*)(fa + mi * (16 * 384) + kc * 32);
#pragma unroll
        for (int ni = 0; ni < 4; ++ni)
            bbf[ni] = *(const short8*)(wb + ni * (16 * 384) + kc * 32);
#pragma unroll
        for (int mi = 0; mi < 4; ++mi)
#pragma unroll
            for (int ni = 0; ni < 4; ++ni)
                acc[mi][ni] = __builtin_amdgcn_mfma_f32_16x16x32_bf16(
                    a[mi], bbf[ni], acc[mi][ni], 0, 0, 0);
    }
#pragma unroll
    for (int ni = 0; ni < 4; ++ni) {
        int n = w * 64 + ni * 16 + lr;
        float bias = b0[n];
#pragma unroll
        for (int mi = 0; mi < 4; ++mi)
#pragma unroll
            for (int r = 0; r < 4; ++r) {
                int m = mi * 16 + lk * 4 + r;
                Hs[m][n] = f2b(fmaxf(acc[mi][ni][r] + bias, 0.f));
            }
    }
    __syncthreads();

    f32x4 acc2[4][2];
#pragma unroll
    for (int mi = 0; mi < 4; ++mi)
#pragma unroll
        for (int ni = 0; ni < 2; ++ni) acc2[mi][ni] = z;

    const us* w1b = W1b + (size_t)(w * 32 + lr) * 256 + lk * 8;
#pragma unroll 4
    for (int kc = 0; kc < 8; ++kc) {
        short8 a2[4], b2[2];
#pragma unroll
        for (int mi = 0; mi < 4; ++mi)
            a2[mi] = *(const short8*)&Hs[mi * 16 + lr][kc * 32 + lk * 8];
#pragma unroll
        for (int ni = 0; ni < 2; ++ni)
            b2[ni] = *(const short8*)(w1b + ni * (16 * 256) + kc * 32);
#pragma unroll
        for (int mi = 0; mi < 4; ++mi)
#pragma unroll
            for (int ni = 0; ni < 2; ++ni)
                acc2[mi][ni] = __builtin_amdgcn_mfma_f32_16x16x32_bf16(
                    a2[mi], b2[ni], acc2[mi][ni], 0, 0, 0);
    }
#pragma unroll
    for (int ni = 0; ni < 2; ++ni) {
        int n = w * 32 + ni * 16 + lr;
        float bias = b1[n];
#pragma unroll
        for (int mi = 0; mi < 4; ++mi)
#pragma unroll
            for (int r = 0; r < 4; ++r) {
                int m = mi * 16 + lk * 4 + r;
                int v = v0 + m;
                if (v < V_) {
                    size_t o = ((size_t)b * V_ + v) * C_ + n;
                    out[o] = acc2[mi][ni][r] + bias + x_in[o];
                }
            }
    }
}

// ============================================================================
extern "C" void kernel_launch(void* const* d_in, const int* in_sizes, int n_in,
                              void* d_out, int out_size, void* d_ws, size_t ws_size,
                              hipStream_t stream)
{
    const float* x_in  = (const float*)d_in[0];
    const float* evals = (const float*)d_in[1];
    const float* evecs = (const float*)d_in[2];
    const float* mass  = (const float*)d_in[3];
    const float* gv[3] = {(const float*)d_in[4], (const float*)d_in[7], (const float*)d_in[10]};
    const int*   gr[3] = {(const int*)d_in[5],   (const int*)d_in[8],   (const int*)d_in[11]};
    const int*   gc[3] = {(const int*)d_in[6],   (const int*)d_in[9],   (const int*)d_in[12]};
    const float* dt  = (const float*)d_in[13];
    const float* Aw  = (const float*)d_in[14];
    const float* W0  = (const float*)d_in[15];
    const float* b0  = (const float*)d_in[16];
    const float* W1  = (const float*)d_in[17];
    const float* b1  = (const float*)d_in[18];
    float* out = (float*)d_out;

    // ---- workspace layout (≈124 MB) ----
    float* x_spec = (float*)d_ws;                            // 65536 f32
    us* spec_t = (us*)(x_spec + 65536);                      // 16384
    us* W0b    = spec_t + 16384;                             // 98304
    us* W1b    = W0b + 98304;                                // 32768
    us* Awb    = W1b + 32768;                                // 147456
    us* fb     = Awb + 147456;                               // VP_*384
    us* vf     = fb + (size_t)VP_ * 384;                     // VP_*384
    us* evT    = vf + (size_t)VP_ * 384;                     // 128*VPT_
    us* mxT    = evT + (size_t)128 * VPT_;                   // 128*VPT_
    uint2* svc = (uint2*)(mxT + (size_t)128 * VPT_);         // 3*NNZ_ uint2
    int* ptr   = (int*)(svc + 3 * (size_t)NNZ_);             // 3*(V_+1)
    int* cnt   = ptr + 3 * (V_ + 1);                         // 3*V_
    int* csum  = cnt + 3 * V_;                               // 3*NCHUNK_

    hipMemsetAsync(x_spec, 0, 65536 * sizeof(float), stream);
    hipMemsetAsync(cnt, 0, 3 * V_ * sizeof(int), stream);    // k_fill re-zeroes it each batch
    k_cvt_all<<<dim3(640), 256, 0, stream>>>(W0, W1, Aw, W0b, W1b, Awb);

    for (int b = 0; b < B_; ++b) {
        k_trans<<<dim3(784), 256, 0, stream>>>(x_in, mass, evecs, mxT, evT, fb, b);
        k_spec_mfma<<<dim3(196), 256, 0, stream>>>(evT, mxT, x_spec, b);
        k_scale2<<<dim3(64), 256, 0, stream>>>(evals, dt, x_spec, spec_t, b);
        k_frombasis_mfma<<<dim3(782), 256, 0, stream>>>(evecs, spec_t, fb, b);
        k_count<<<dim3(3125, 3), 256, 0, stream>>>(gr[0], gr[1], gr[2], cnt, b);
        k_chunksum<<<dim3(NCHUNK_, 3), 256, 0, stream>>>(cnt, csum);
        k_chunkscan<<<dim3(1), 64, 0, stream>>>(csum, ptr);
        k_ptrwrite<<<dim3(NCHUNK_, 3), 256, 0, stream>>>(cnt, csum, ptr);
        k_fill<<<dim3(3125, 3, NSLICE_), 256, 0, stream>>>(
            gr[0], gr[1], gr[2], gc[0], gc[1], gc[2], gv[0], gv[1], gv[2],
            ptr, cnt, svc, b);
        k_gather<<<dim3(12500, 3), 256, 0, stream>>>(svc, ptr, fb, vf);
        k_gf_mfma<<<dim3(782), 256, 0, stream>>>(vf, Awb, fb);
        k_mlp_mfma<<<dim3(782), 256, 0, stream>>>(fb, W0b, b0, W1b, b1, x_in, out, b);
    }
}